// Round 9
// baseline (311.383 us; speedup 1.0000x reference)
//
#include <hip/hip_runtime.h>

#define E_DIM 65536
#define BE_TOTAL 524288
#define EPS_BN 1e-5f
#define NB_STATS 256

typedef unsigned int uint;
typedef unsigned short ushort;
typedef __attribute__((ext_vector_type(8))) short short8;   // 8 bf16 (4 VGPR)
typedef __attribute__((ext_vector_type(4))) float floatx4;

#define PSTR ((size_t)BE_TOTAL*16)   // ushort stride of one 16-ch plane

__device__ __forceinline__ float bflo(uint u){ return __uint_as_float(u << 16); }
__device__ __forceinline__ float bfhi(uint u){ return __uint_as_float(u & 0xffff0000u); }

__device__ __forceinline__ ushort pbf1(float a){
  uint ua = __float_as_uint(a);
  return (ushort)((ua + 0x7fffu + ((ua >> 16) & 1u)) >> 16);
}
__device__ __forceinline__ uint packbf(float a, float b){
  return (uint)pbf1(a) | ((uint)pbf1(b) << 16);
}
__device__ __forceinline__ void unpack8(uint4 v, float* x){
  x[0]=bflo(v.x); x[1]=bfhi(v.x); x[2]=bflo(v.y); x[3]=bfhi(v.y);
  x[4]=bflo(v.z); x[5]=bfhi(v.z); x[6]=bflo(v.w); x[7]=bfhi(v.w);
}
__device__ __forceinline__ uint4 pack8u(const float* z){
  uint4 v;
  v.x = packbf(z[0],z[1]); v.y = packbf(z[2],z[3]);
  v.z = packbf(z[4],z[5]); v.w = packbf(z[6],z[7]);
  return v;
}

// ------------- weight relayout: unified 16-ch chunks, KSTEPS=3 -------------
// image: [chunk*3+ks][o][32 kvals] bf16; k-layout: ft=ks*2+(j>>4), ci=chunk*16+(j&15)
template<int CI, int CO>
__global__ void wprep(const float* __restrict__ w, ushort* __restrict__ img)
{
  constexpr int CHUNKS = CI/16;
  const int t = blockIdx.x*256 + threadIdx.x;
  if (t >= CHUNKS*3*CO*4) return;
  const int s  = t & 3;
  const int o  = (t >> 2) % CO;
  const int ck = (t >> 2) / CO;           // chunk*3 + ks
  const int chunk = ck / 3;
  const int ks    = ck % 3;
  float z[8];
  #pragma unroll
  for (int j8=0;j8<8;j8++){
    const int j = s*8 + j8;
    const int ft = ks*2 + (j>>4);
    const int ci = chunk*16 + (j & 15);
    z[j8] = (ft < 5) ? w[((size_t)o*CI + ci)*5 + ft] : 0.f;
  }
  const int t4 = (o&3) ^ ((o>>2)&3);
  *reinterpret_cast<uint4*>(img + ((size_t)(ck*CO + o))*32 + ((s^t4)<<3)) = pack8u(z);
}

// ---------------- MFMA mesh-conv (fused BN-stats epilogue) ----------------
// Input: CI/16 planes of [b][e][16] bf16. Output: CO/16 planes (PLANES_OUT)
// or linear [b][e][CO] (for h3). F in LDS: [3 ks][128 el][32 k] bf16,
// 16B-slot XOR swizzle. B-fragments straight from pre-swizzled global image.
// Next chunk's gather rows are prefetched into registers while the current
// chunk's F-build + MFMA run (T14 issue-early).
template<int CI, int CO, bool PLANES_OUT>
__launch_bounds__(256, 4)
__global__ void mconv_mfma(const ushort* __restrict__ hin,
                           const int* __restrict__ gemm,
                           const ushort* __restrict__ wimg,
                           const float* __restrict__ bias,
                           const float* __restrict__ ss,
                           ushort* __restrict__ hout,
                           float* __restrict__ spart)
{
  constexpr int CHUNKS = CI/16;
  constexpr int NT = CO/16;
  __shared__ char smem[24576];
  char* FB = smem;

  const int tid = threadIdx.x;
  const int bid = blockIdx.x;            // 4096 = 8 (batch=XCD) * 512
  const int b   = bid & 7;
  const int e0  = (bid >> 3) * 128;
  const size_t bbase = (size_t)b << 16;

  // MFMA lane constants
  const int lane = tid & 63;
  const int wv   = tid >> 6;
  const int col  = lane & 15;
  const int kg   = lane >> 4;
  const int t4c  = (col & 3) ^ ((col >> 2) & 3);
  const int loff = col*64 + ((kg ^ t4c) << 4);

  floatx4 acc[2][NT];
  #pragma unroll
  for (int n=0;n<NT;n++){
    const float bv = bias[n*16 + col];
    #pragma unroll
    for (int mt=0;mt<2;mt++) acc[mt][n] = (floatx4){bv,bv,bv,bv};
  }

  // gather offsets (within a plane): 2 threads/element, hh = 8-ch half
  const int el = tid >> 1;
  const int hh = tid & 1;
  const int t4e = (el&3) ^ ((el>>2)&3);
  uint off[5];
  {
    const size_t idx = bbase + (size_t)(e0 + el);
    const int4 g4 = *reinterpret_cast<const int4*>(gemm + idx*4);
    off[0] = (uint)(idx*16 + hh*8);
    off[1] = (uint)((bbase + (size_t)(uint)g4.x)*16 + hh*8);
    off[2] = (uint)((bbase + (size_t)(uint)g4.y)*16 + hh*8);
    off[3] = (uint)((bbase + (size_t)(uint)g4.z)*16 + hh*8);
    off[4] = (uint)((bbase + (size_t)(uint)g4.w)*16 + hh*8);
  }

  // prefetch chunk 0's rows
  uint4 q[5];
  #pragma unroll
  for (int r=0;r<5;r++) q[r] = *reinterpret_cast<const uint4*>(hin + off[r]);

  for (int chunk=0; chunk<CHUNKS; ++chunk){
    if (chunk > 0) __syncthreads();      // prev MFMA done before FB overwrite

    // ---- consume q, then immediately issue next chunk's loads ----
    float v[5][8];
    #pragma unroll
    for (int r=0;r<5;r++) unpack8(q[r], v[r]);

    if (chunk+1 < CHUNKS){
      const ushort* hp = hin + (size_t)(chunk+1)*PSTR;
      #pragma unroll
      for (int r=0;r<5;r++) q[r] = *reinterpret_cast<const uint4*>(hp + off[r]);
    }

    // ---- build F in LDS (8 channels per thread) ----
    {
      const int cb = chunk*16 + hh*8;
      #pragma unroll
      for (int c=0;c<8;c++){
        const float sc = ss[cb+c], sh = ss[CI+cb+c];
        #pragma unroll
        for (int r=0;r<5;r++) v[r][c] = fmaxf(fmaf(v[r][c], sc, sh), 0.f);
      }
      float y[5][8];
      #pragma unroll
      for (int c=0;c<8;c++){
        y[0][c] = v[0][c];
        y[1][c] = v[1][c] + v[3][c];
        y[2][c] = v[2][c] + v[4][c];
        y[3][c] = fabsf(v[1][c] - v[3][c]);
        y[4][c] = fabsf(v[2][c] - v[4][c]);
      }
      #pragma unroll
      for (int ks=0; ks<3; ks++){
        char* base = FB + ks*8192 + el*64;
        *reinterpret_cast<uint4*>(base + (((0+hh)^t4e)<<4)) = pack8u(y[2*ks]);
        if (ks < 2){
          *reinterpret_cast<uint4*>(base + (((2+hh)^t4e)<<4)) = pack8u(y[2*ks+1]);
        } else {
          const uint4 zz = {0,0,0,0};
          *reinterpret_cast<uint4*>(base + (((2+hh)^t4e)<<4)) = zz;
        }
      }
    }
    __syncthreads();

    // ---- MFMA (B-fragments from global image, L1/L2-hot) ----
    const char* WG = reinterpret_cast<const char*>(wimg) + (size_t)chunk*(3*CO*64);
    #pragma unroll
    for (int ks=0; ks<3; ks++){
      short8 bf[NT];
      #pragma unroll
      for (int n=0;n<NT;n++)
        bf[n] = *reinterpret_cast<const short8*>(WG + ks*(CO*64) + n*1024 + loff);
      #pragma unroll
      for (int mt=0;mt<2;mt++){
        const short8 af = *reinterpret_cast<const short8*>(FB + ks*8192 + (wv*32+mt*16)*64 + loff);
        #pragma unroll
        for (int n=0;n<NT;n++)
          acc[mt][n] = __builtin_amdgcn_mfma_f32_16x16x32_bf16(af, bf[n], acc[mt][n], 0, 0, 0);
      }
    }
  }

  // ---- per-lane BN-stats partials (registers only) ----
  float sred[2*NT];
  #pragma unroll
  for (int n=0;n<NT;n++){
    float s = 0.f, q2 = 0.f;
    #pragma unroll
    for (int mt=0;mt<2;mt++){
      #pragma unroll
      for (int r=0;r<4;r++){ const float vv = acc[mt][n][r]; s += vv; q2 = fmaf(vv,vv,q2); }
    }
    s  += __shfl_xor(s,16,64);  s  += __shfl_xor(s,32,64);
    q2 += __shfl_xor(q2,16,64); q2 += __shfl_xor(q2,32,64);
    sred[n] = s; sred[NT+n] = q2;
  }

  __syncthreads();
  // epilogue: repack D through LDS + stage stats partials
  ushort* OB = reinterpret_cast<ushort*>(smem);
  float*  SB = reinterpret_cast<float*>(smem + 128*CO*2);   // [4][2*CO]
  #pragma unroll
  for (int mt=0; mt<2; mt++){
    const int er = wv*32 + mt*16 + 4*kg;
    #pragma unroll
    for (int n=0;n<NT;n++){
      #pragma unroll
      for (int r=0;r<4;r++)
        OB[(er+r)*CO + n*16 + col] = pbf1(acc[mt][n][r]);
    }
  }
  if (kg == 0){
    #pragma unroll
    for (int n=0;n<NT;n++){
      SB[wv*2*CO + n*16 + col]      = sred[n];
      SB[wv*2*CO + CO + n*16 + col] = sred[NT+n];
    }
  }
  __syncthreads();
  if constexpr (PLANES_OUT){
    constexpr int SLOTS = CO/8;                 // 8-ch uint4 slots per row
    const uint4* src = reinterpret_cast<const uint4*>(smem);
    constexpr int NV = 128*CO/8;
    for (int i=tid; i<NV; i+=256){
      const int row  = i / SLOTS;
      const int slot = i % SLOTS;
      const int pl   = slot >> 1;
      const int half = slot & 1;
      *reinterpret_cast<uint4*>(hout + (size_t)pl*PSTR + (bbase + (size_t)(e0+row))*16 + half*8) = src[i];
    }
  } else {
    const uint4* src = reinterpret_cast<const uint4*>(smem);
    uint4* dst = reinterpret_cast<uint4*>(hout + (bbase + (size_t)e0)*CO);
    constexpr int NV = 128*CO/8;
    for (int i=tid; i<NV; i+=256) dst[i] = src[i];
  }
  if (tid < 2*CO){
    spart[(size_t)bid*2*CO + tid] =
      SB[tid] + SB[2*CO + tid] + SB[4*CO + tid] + SB[6*CO + tid];
  }
}

// ---------------- conv0: CI=5 (padded-8 rows) -> CO=16, VALU ----------------
__launch_bounds__(256)
__global__ void conv0_kernel(const ushort* __restrict__ hin,
                             const int* __restrict__ gemm,
                             const float* __restrict__ w,
                             const float* __restrict__ bias,
                             ushort* __restrict__ hout)
{
  const int bid = blockIdx.x;                     // 2048 = 8 XCD * 256
  const int swz = (bid & 7) * 256 + (bid >> 3);
  const int idx = swz * 256 + threadIdx.x;
  const int b = idx >> 16;
  const int4 g4 = *reinterpret_cast<const int4*>(gemm + (size_t)idx * 4);
  const size_t bbase = (size_t)b << 16;
  float xc[8], n0[8], n1[8], n2[8], n3[8];
  unpack8(*reinterpret_cast<const uint4*>(hin + (size_t)idx*8), xc);
  unpack8(*reinterpret_cast<const uint4*>(hin + (bbase + (size_t)(uint)g4.x)*8), n0);
  unpack8(*reinterpret_cast<const uint4*>(hin + (bbase + (size_t)(uint)g4.y)*8), n1);
  unpack8(*reinterpret_cast<const uint4*>(hin + (bbase + (size_t)(uint)g4.z)*8), n2);
  unpack8(*reinterpret_cast<const uint4*>(hin + (bbase + (size_t)(uint)g4.w)*8), n3);
  float f1[5], f2[5], f3[5], f4[5];
  #pragma unroll
  for (int c=0;c<5;c++){
    f1[c] = n0[c] + n2[c];
    f2[c] = n1[c] + n3[c];
    f3[c] = fabsf(n0[c] - n2[c]);
    f4[c] = fabsf(n1[c] - n3[c]);
  }
  float acc[16];
  #pragma unroll
  for (int o=0;o<16;o++){
    const float* wp = w + (size_t)o*25;
    float a = bias[o];
    #pragma unroll
    for (int c=0;c<5;c++){
      a = fmaf(xc[c], wp[c*5+0], a);
      a = fmaf(f1[c], wp[c*5+1], a);
      a = fmaf(f2[c], wp[c*5+2], a);
      a = fmaf(f3[c], wp[c*5+3], a);
      a = fmaf(f4[c], wp[c*5+4], a);
    }
    acc[o] = a;
  }
  #pragma unroll
  for (int o=0;o<16;o+=8){
    uint4 v;
    v.x = packbf(acc[o+0], acc[o+1]);
    v.y = packbf(acc[o+2], acc[o+3]);
    v.z = packbf(acc[o+4], acc[o+5]);
    v.w = packbf(acc[o+6], acc[o+7]);
    *reinterpret_cast<uint4*>(hout + (size_t)idx * 16 + o) = v;
  }
}

// ---------------- BN stats / merge / finalize / pool / fc --------------
template<int CO>
__launch_bounds__(256)
__global__ void stats_kernel(const ushort* __restrict__ h, float* __restrict__ part)
{
  constexpr int GROUPS = CO / 8;
  constexpr int ROWS   = 256 / GROUPS;
  const int tid = threadIdx.x;
  const int cg  = tid % GROUPS;
  const int row = tid / GROUPS;
  float s[8], q[8];
  #pragma unroll
  for (int i=0;i<8;i++){ s[i]=0.f; q[i]=0.f; }
  for (long idx = (long)blockIdx.x*ROWS + row; idx < BE_TOTAL; idx += (long)gridDim.x*ROWS){
    uint4 v = *reinterpret_cast<const uint4*>(h + (size_t)idx*CO + cg*8);
    float x[8]; unpack8(v, x);
    #pragma unroll
    for (int i=0;i<8;i++){ s[i]+=x[i]; q[i]+=x[i]*x[i]; }
  }
  __shared__ float lds[256*16];
  #pragma unroll
  for (int i=0;i<8;i++){ lds[tid*16+i]=s[i]; lds[tid*16+8+i]=q[i]; }
  __syncthreads();
  if (tid < 2*CO){
    const int st = tid / CO;
    const int c  = tid % CO;
    const int cgg = c >> 3, ci = c & 7;
    float t = 0.f;
    for (int r=0;r<ROWS;r++) t += lds[(r*GROUPS+cgg)*16 + st*8 + ci];
    part[(size_t)blockIdx.x*(2*CO) + tid] = t;
  }
}

// merge 4096 per-block partial rows -> 128 rows (coalesced)
template<int CO>
__launch_bounds__(256)
__global__ void merge_stats(const float* __restrict__ in, float* __restrict__ out)
{
  const int t = threadIdx.x;
  if (t >= 2*CO) return;
  const int j = blockIdx.x;            // 128
  float s = 0.f;
  #pragma unroll 4
  for (int r = 0; r < 32; r++) s += in[((size_t)(j*32 + r))*(2*CO) + t];
  out[(size_t)j*(2*CO) + t] = s;
}

// Parallel finalize: 256 threads, Q=256/CO lanes per channel.
template<int CO>
__launch_bounds__(256)
__global__ void finalize_stats(const float* __restrict__ part, int nblk,
                               const float* __restrict__ g, const float* __restrict__ beta,
                               float* __restrict__ ss)
{
  constexpr int Q = 256 / CO;
  const int t = threadIdx.x;
  const int c = t % CO;
  const int qq = t / CO;
  float s = 0.f, sq = 0.f;
  for (int b = qq; b < nblk; b += Q){
    s  += part[(size_t)b*2*CO + c];
    sq += part[(size_t)b*2*CO + CO + c];
  }
  __shared__ float lsum[256], lsq[256];
  lsum[t] = s; lsq[t] = sq;
  __syncthreads();
  if (t < CO){
    float ts = 0.f, tq = 0.f;
    #pragma unroll
    for (int r = 0; r < Q; r++){ ts += lsum[r*CO + t]; tq += lsq[r*CO + t]; }
    const float inv = 1.f / (float)BE_TOTAL;
    const float mean = ts * inv;
    const float var  = tq * inv - mean*mean;
    const float scale = g[t] * rsqrtf(var + EPS_BN);
    ss[t]      = scale;
    ss[CO + t] = beta[t] - mean * scale;
  }
}

__launch_bounds__(256)
__global__ void pool_kernel(const ushort* __restrict__ h3, const float* __restrict__ ss,
                            float* __restrict__ part)
{
  const int tid = threadIdx.x;
  const int cg  = tid % 8;
  const int row = tid / 8;
  const int b   = blockIdx.x >> 6;
  const int blk = blockIdx.x & 63;
  float sc[8], sh[8];
  #pragma unroll
  for (int i=0;i<8;i++){ sc[i]=ss[cg*8+i]; sh[i]=ss[64+cg*8+i]; }
  float s[8];
  #pragma unroll
  for (int i=0;i<8;i++) s[i]=0.f;
  for (int e = blk*32 + row; e < E_DIM; e += 64*32){
    size_t idx = ((size_t)b << 16) + e;
    uint4 v = *reinterpret_cast<const uint4*>(h3 + idx*64 + cg*8);
    float x[8]; unpack8(v, x);
    #pragma unroll
    for (int i=0;i<8;i++) s[i] += fmaxf(fmaf(x[i], sc[i], sh[i]), 0.f);
  }
  __shared__ float lds[256*8];
  #pragma unroll
  for (int i=0;i<8;i++) lds[tid*8+i]=s[i];
  __syncthreads();
  if (tid < 64){
    const int c = tid, cgg = c >> 3, ci = c & 7;
    float t = 0.f;
    for (int r=0;r<32;r++) t += lds[(r*8+cgg)*8 + ci];
    part[((size_t)b*64 + blk)*64 + c] = t;
  }
}

__global__ void finalize_pool(const float* __restrict__ part, float* __restrict__ pooled)
{
  const int t = threadIdx.x;
  const int b = t >> 6, c = t & 63;
  float s = 0.f;
  for (int blk=0;blk<64;blk++) s += part[((size_t)b*64 + blk)*64 + c];
  pooled[t] = s * (1.f / (float)E_DIM);
}

// fc1: writes h1t in (n, b) layout for coalesced fc2
__global__ void fc1_kernel(const float* __restrict__ pooled, const float* __restrict__ dw1,
                           const float* __restrict__ db1, float* __restrict__ h1t)
{
  const int n = blockIdx.x*blockDim.x + threadIdx.x;
  if (n >= 2500) return;
  float acc[8];
  const float bias = db1[n];
  #pragma unroll
  for (int b=0;b<8;b++) acc[b]=bias;
  const float* wr = dw1 + (size_t)n*64;
  #pragma unroll
  for (int c=0;c<64;c++){
    float wv = wr[c];
    #pragma unroll
    for (int b=0;b<8;b++) acc[b] = fmaf(wv, pooled[b*64+c], acc[b]);
  }
  #pragma unroll
  for (int b=0;b<8;b++) h1t[(size_t)n*8 + b] = fmaxf(acc[b], 0.f);
}

// fc2: one wave per output row m, coalesced float4 dw2 reads, butterfly reduce
__launch_bounds__(256)
__global__ void fc2_kernel(const float* __restrict__ h1t, const float* __restrict__ dw2,
                           const float* __restrict__ db2, const float* __restrict__ oldv,
                           float* __restrict__ out)
{
  const int wv   = threadIdx.x >> 6;        // 4 waves/block
  const int lane = threadIdx.x & 63;
  const int m = blockIdx.x*4 + wv;
  if (m >= 1926) return;
  const float4* wr = reinterpret_cast<const float4*>(dw2 + (size_t)m*2500);
  float acc[8];
  #pragma unroll
  for (int b=0;b<8;b++) acc[b]=0.f;
  for (int j = lane; j < 625; j += 64){
    const float4 w4 = wr[j];
    const float4* hp = reinterpret_cast<const float4*>(h1t + (size_t)j*32);
    const float4 h0a = hp[0], h0b = hp[1];
    const float4 h1a = hp[2], h1b = hp[3];
    const float4 h2a = hp[4], h2b = hp[5];
    const float4 h3a = hp[6], h3b = hp[7];
    acc[0] = fmaf(w4.x, h0a.x, fmaf(w4.y, h1a.x, fmaf(w4.z, h2a.x, fmaf(w4.w, h3a.x, acc[0]))));
    acc[1] = fmaf(w4.x, h0a.y, fmaf(w4.y, h1a.y, fmaf(w4.z, h2a.y, fmaf(w4.w, h3a.y, acc[1]))));
    acc[2] = fmaf(w4.x, h0a.z, fmaf(w4.y, h1a.z, fmaf(w4.z, h2a.z, fmaf(w4.w, h3a.z, acc[2]))));
    acc[3] = fmaf(w4.x, h0a.w, fmaf(w4.y, h1a.w, fmaf(w4.z, h2a.w, fmaf(w4.w, h3a.w, acc[3]))));
    acc[4] = fmaf(w4.x, h0b.x, fmaf(w4.y, h1b.x, fmaf(w4.z, h2b.x, fmaf(w4.w, h3b.x, acc[4]))));
    acc[5] = fmaf(w4.x, h0b.y, fmaf(w4.y, h1b.y, fmaf(w4.z, h2b.y, fmaf(w4.w, h3b.y, acc[5]))));
    acc[6] = fmaf(w4.x, h0b.z, fmaf(w4.y, h1b.z, fmaf(w4.z, h2b.z, fmaf(w4.w, h3b.z, acc[6]))));
    acc[7] = fmaf(w4.x, h0b.w, fmaf(w4.y, h1b.w, fmaf(w4.z, h2b.w, fmaf(w4.w, h3b.w, acc[7]))));
  }
  #pragma unroll
  for (int s=1; s<64; s<<=1){
    #pragma unroll
    for (int b=0;b<8;b++) acc[b] += __shfl_xor(acc[b], s, 64);
  }
  if (lane == 0){
    const float bm = db2[m];
    #pragma unroll
    for (int b=0;b<8;b++){
      const int t = b*1926 + m;
      out[t] = acc[b] + bm + oldv[t];
    }
  }
}

__launch_bounds__(256)
__global__ void transpose_x(const float* __restrict__ x, ushort* __restrict__ xt)
{
  const int idx = blockIdx.x*256 + threadIdx.x;
  const int b = idx >> 16, e = idx & 65535;
  const float* xb = x + (size_t)b*5*E_DIM + e;
  uint4 v;
  v.x = packbf(xb[0],               xb[(size_t)E_DIM]);
  v.y = packbf(xb[2*(size_t)E_DIM], xb[3*(size_t)E_DIM]);
  v.z = packbf(xb[4*(size_t)E_DIM], 0.f);
  v.w = 0u;
  *reinterpret_cast<uint4*>(xt + (size_t)idx*8) = v;
}

extern "C" void kernel_launch(void* const* d_in, const int* in_sizes, int n_in,
                              void* d_out, int out_size, void* d_ws, size_t ws_size,
                              hipStream_t stream)
{
  const float* x    = (const float*)d_in[0];
  const int*   gm   = (const int*)d_in[1];
  const float* oldv = (const float*)d_in[2];
  const float* w0 = (const float*)d_in[3],  *b0 = (const float*)d_in[4];
  const float* g0 = (const float*)d_in[5],  *be0= (const float*)d_in[6];
  const float* w1 = (const float*)d_in[7],  *b1 = (const float*)d_in[8];
  const float* g1 = (const float*)d_in[9],  *be1= (const float*)d_in[10];
  const float* w2 = (const float*)d_in[11], *b2 = (const float*)d_in[12];
  const float* g2 = (const float*)d_in[13], *be2= (const float*)d_in[14];
  const float* w3 = (const float*)d_in[15], *b3 = (const float*)d_in[16];
  const float* g3 = (const float*)d_in[17], *be3= (const float*)d_in[18];
  const float* dw1 = (const float*)d_in[19], *db1 = (const float*)d_in[20];
  const float* dw2 = (const float*)d_in[21], *db2 = (const float*)d_in[22];

  char* ws = (char*)d_ws;
  size_t off = 0;
  auto alloc = [&](size_t n){ size_t o = off; off += (n + 255) & ~(size_t)255; return o; };
  ushort* xt = (ushort*)(ws + alloc((size_t)BE_TOTAL*8*2));
  ushort* h0 = (ushort*)(ws + alloc((size_t)BE_TOTAL*16*2));
  ushort* h1 = (ushort*)(ws + alloc((size_t)BE_TOTAL*32*2));   // 2 planes
  ushort* h2 = (ushort*)(ws + alloc((size_t)BE_TOTAL*64*2));   // 4 planes
  ushort* h3 = (ushort*)(ws + alloc((size_t)BE_TOTAL*64*2));   // linear
  float* part   = (float*)(ws + alloc((size_t)NB_STATS*128*4));
  float* spart  = (float*)(ws + alloc((size_t)4096*128*4));
  float* mpart  = (float*)(ws + alloc((size_t)128*128*4));
  float* ss0    = (float*)(ws + alloc(512));
  float* ss1    = (float*)(ws + alloc(512));
  float* ss2    = (float*)(ws + alloc(512));
  float* ss3    = (float*)(ws + alloc(512));
  float* ppart  = (float*)(ws + alloc((size_t)8*64*64*4));
  float* pooled = (float*)(ws + alloc(512*4));
  float* h1fc   = (float*)(ws + alloc(20000*4));
  ushort* w1i   = (ushort*)(ws + alloc((size_t)3*32*32*2));
  ushort* w2i   = (ushort*)(ws + alloc((size_t)6*64*32*2));
  ushort* w3i   = (ushort*)(ws + alloc((size_t)12*64*32*2));
  (void)ws_size; (void)in_sizes; (void)n_in; (void)out_size;

  const int CB = BE_TOTAL/256;   // 2048
  const int MB = BE_TOTAL/128;   // 4096

  transpose_x<<<CB,256,0,stream>>>(x, xt);
  wprep<16,32><<<2,256,0,stream>>>(w1, w1i);
  wprep<32,64><<<6,256,0,stream>>>(w2, w2i);
  wprep<64,64><<<12,256,0,stream>>>(w3, w3i);

  conv0_kernel<<<CB,256,0,stream>>>(xt, gm, w0, b0, h0);
  stats_kernel<16><<<NB_STATS,256,0,stream>>>(h0, part);
  finalize_stats<16><<<1,256,0,stream>>>(part, NB_STATS, g0, be0, ss0);

  mconv_mfma<16,32,true><<<MB,256,0,stream>>>(h0, gm, w1i, b1, ss0, h1, spart);
  merge_stats<32><<<128,256,0,stream>>>(spart, mpart);
  finalize_stats<32><<<1,256,0,stream>>>(mpart, 128, g1, be1, ss1);

  mconv_mfma<32,64,true><<<MB,256,0,stream>>>(h1, gm, w2i, b2, ss1, h2, spart);
  merge_stats<64><<<128,256,0,stream>>>(spart, mpart);
  finalize_stats<64><<<1,256,0,stream>>>(mpart, 128, g2, be2, ss2);

  mconv_mfma<64,64,false><<<MB,256,0,stream>>>(h2, gm, w3i, b3, ss2, h3, spart);
  merge_stats<64><<<128,256,0,stream>>>(spart, mpart);
  finalize_stats<64><<<1,256,0,stream>>>(mpart, 128, g3, be3, ss3);

  pool_kernel<<<512,256,0,stream>>>(h3, ss3, ppart);
  finalize_pool<<<1,512,0,stream>>>(ppart, pooled);
  fc1_kernel<<<10,256,0,stream>>>(pooled, dw1, db1, h1fc);
  fc2_kernel<<<482,256,0,stream>>>(h1fc, dw2, db2, oldv, (float*)d_out);
}

// Round 11
// 252.046 us; speedup vs baseline: 1.2354x; 1.2354x over previous
//
#include <hip/hip_runtime.h>

#define E_DIM 65536
#define BE_TOTAL 524288
#define EPS_BN 1e-5f
#define NB_STATS 256

typedef unsigned int uint;
typedef unsigned short ushort;
typedef unsigned char uchar;
typedef __attribute__((ext_vector_type(8))) short short8;   // 8 bf16 (4 VGPR)
typedef __attribute__((ext_vector_type(4))) float floatx4;

#define PB_FP8 ((size_t)BE_TOTAL*16)   // bytes per 16-ch fp8 plane

__device__ __forceinline__ float bflo(uint u){ return __uint_as_float(u << 16); }
__device__ __forceinline__ float bfhi(uint u){ return __uint_as_float(u & 0xffff0000u); }

__device__ __forceinline__ ushort pbf1(float a){
  uint ua = __float_as_uint(a);
  return (ushort)((ua + 0x7fffu + ((ua >> 16) & 1u)) >> 16);
}
__device__ __forceinline__ uint packbf(float a, float b){
  return (uint)pbf1(a) | ((uint)pbf1(b) << 16);
}
__device__ __forceinline__ void unpack8(uint4 v, float* x){
  x[0]=bflo(v.x); x[1]=bfhi(v.x); x[2]=bflo(v.y); x[3]=bfhi(v.y);
  x[4]=bflo(v.z); x[5]=bfhi(v.z); x[6]=bflo(v.w); x[7]=bfhi(v.w);
}
__device__ __forceinline__ uint4 pack8u(const float* z){
  uint4 v;
  v.x = packbf(z[0],z[1]); v.y = packbf(z[2],z[3]);
  v.z = packbf(z[4],z[5]); v.w = packbf(z[6],z[7]);
  return v;
}

// ---- fp8 e4m3 helpers ----
__device__ __forceinline__ uint2 pack8f8(const float* z){
  int lo = __builtin_amdgcn_cvt_pk_fp8_f32(z[0], z[1], 0,  false);
  lo     = __builtin_amdgcn_cvt_pk_fp8_f32(z[2], z[3], lo, true);
  int hi = __builtin_amdgcn_cvt_pk_fp8_f32(z[4], z[5], 0,  false);
  hi     = __builtin_amdgcn_cvt_pk_fp8_f32(z[6], z[7], hi, true);
  uint2 r; r.x = (uint)lo; r.y = (uint)hi; return r;
}
__device__ __forceinline__ void dec8f8(uint2 w, float* x){
  x[0]=__builtin_amdgcn_cvt_f32_fp8((int)w.x,0);
  x[1]=__builtin_amdgcn_cvt_f32_fp8((int)w.x,1);
  x[2]=__builtin_amdgcn_cvt_f32_fp8((int)w.x,2);
  x[3]=__builtin_amdgcn_cvt_f32_fp8((int)w.x,3);
  x[4]=__builtin_amdgcn_cvt_f32_fp8((int)w.y,0);
  x[5]=__builtin_amdgcn_cvt_f32_fp8((int)w.y,1);
  x[6]=__builtin_amdgcn_cvt_f32_fp8((int)w.y,2);
  x[7]=__builtin_amdgcn_cvt_f32_fp8((int)w.y,3);
}
__device__ __forceinline__ uchar f8byte(float v){
  return (uchar)(__builtin_amdgcn_cvt_pk_fp8_f32(v, 0.f, 0, false) & 0xff);
}

// ------------- weight relayout (bf16 image, layer1): 16-ch chunks, KSTEPS=3 ----
template<int CI, int CO>
__global__ void wprep(const float* __restrict__ w, ushort* __restrict__ img)
{
  constexpr int CHUNKS = CI/16;
  const int t = blockIdx.x*256 + threadIdx.x;
  if (t >= CHUNKS*3*CO*4) return;
  const int s  = t & 3;
  const int o  = (t >> 2) % CO;
  const int ck = (t >> 2) / CO;
  const int chunk = ck / 3;
  const int ks    = ck % 3;
  float z[8];
  #pragma unroll
  for (int j8=0;j8<8;j8++){
    const int j = s*8 + j8;
    const int ft = ks*2 + (j>>4);
    const int ci = chunk*16 + (j & 15);
    z[j8] = (ft < 5) ? w[((size_t)o*CI + ci)*5 + ft] : 0.f;
  }
  const int t4 = (o&3) ^ ((o>>2)&3);
  *reinterpret_cast<uint4*>(img + ((size_t)(ck*CO + o))*32 + ((s^t4)<<3)) = pack8u(z);
}

// ------------- weight relayout (fp8 image, layers 2/3): rows 32B, groups 8B ----
template<int CI, int CO>
__global__ void wprep8(const float* __restrict__ w, uchar* __restrict__ img)
{
  constexpr int CHUNKS = CI/16;
  const int t = blockIdx.x*256 + threadIdx.x;
  if (t >= CHUNKS*3*CO*4) return;
  const int g  = t & 3;
  const int o  = (t >> 2) % CO;
  const int ck = (t >> 2) / CO;
  const int chunk = ck / 3;
  const int ks    = ck % 3;
  float z[8];
  #pragma unroll
  for (int j8=0;j8<8;j8++){
    const int j = g*8 + j8;
    const int ft = ks*2 + (j>>4);
    const int ci = chunk*16 + (j & 15);
    z[j8] = (ft < 5) ? w[((size_t)o*CI + ci)*5 + ft] * 64.f : 0.f;   // SW=64
  }
  const int t4 = (o&3) ^ ((o>>2)&3);
  *reinterpret_cast<uint2*>(img + ((size_t)(ck*CO + o))*32 + ((g^t4)<<3)) = pack8f8(z);
}

// ---------------- MFMA mesh-conv (fused BN-stats epilogue) ----------------
// Input: CI/16 planes, bf16 (32B rows) or fp8 (16B rows). Output: fp8 planes
// or bf16 linear (h3). F in LDS: [3 ks][128 el][32 k], rows 64B (bf16) /
// 32B (fp8), slot/group XOR swizzle. B-fragments from pre-swizzled global.
template<int CI, int CO, bool IN_FP8, bool OUT_BF16LIN>
__launch_bounds__(256, 4)
__global__ void mconv_mfma(const char* __restrict__ hin,
                           const int* __restrict__ gemm,
                           const char* __restrict__ wimg,
                           const float* __restrict__ bias, float bscale,
                           const float* __restrict__ ss, float pkf,
                           char* __restrict__ hout,
                           float* __restrict__ spart)
{
  constexpr int CHUNKS = CI/16;
  constexpr int NT = CO/16;
  constexpr int AB  = IN_FP8 ? 32 : 64;               // FB row bytes
  constexpr int FBY = 3*128*AB;
  constexpr int OBB = 128*CO*(OUT_BF16LIN?2:1);
  constexpr int SBY = 4*2*CO*4;
  constexpr int SMEM = (FBY > OBB+SBY) ? FBY : (OBB+SBY);
  constexpr size_t PIN = IN_FP8 ? PB_FP8 : (size_t)BE_TOTAL*32;
  constexpr int RB = IN_FP8 ? 16 : 32;                // input row bytes
  __shared__ char smem[SMEM];
  char* FB = smem;

  const int tid = threadIdx.x;
  const int bid = blockIdx.x;            // 4096 = 8 (batch=XCD) * 512
  const int b   = bid & 7;
  const int e0  = (bid >> 3) * 128;
  const size_t bbase = (size_t)b << 16;

  const int lane = tid & 63;
  const int wv   = tid >> 6;
  const int col  = lane & 15;
  const int kg   = lane >> 4;
  const int t4c  = (col & 3) ^ ((col >> 2) & 3);

  floatx4 acc[2][NT];
  #pragma unroll
  for (int n=0;n<NT;n++){
    const float bv = bias[n*16 + col] * bscale;
    #pragma unroll
    for (int mt=0;mt<2;mt++) acc[mt][n] = (floatx4){bv,bv,bv,bv};
  }

  // gather byte-offsets within a plane: 2 threads/element, hh = 8-ch half
  const int el = tid >> 1;
  const int hh = tid & 1;
  const int t4e = (el&3) ^ ((el>>2)&3);
  uint off[5];
  {
    const size_t idx = bbase + (size_t)(e0 + el);
    const int4 g4 = *reinterpret_cast<const int4*>(gemm + idx*4);
    off[0] = (uint)(idx*RB + hh*(RB/2));
    off[1] = (uint)((bbase + (size_t)(uint)g4.x)*RB + hh*(RB/2));
    off[2] = (uint)((bbase + (size_t)(uint)g4.y)*RB + hh*(RB/2));
    off[3] = (uint)((bbase + (size_t)(uint)g4.z)*RB + hh*(RB/2));
    off[4] = (uint)((bbase + (size_t)(uint)g4.w)*RB + hh*(RB/2));
  }

  for (int chunk=0; chunk<CHUNKS; ++chunk){
    if (chunk > 0) __syncthreads();      // prev MFMA done before FB overwrite

    // ---- load + decode gather rows (8 channels per thread) ----
    float v[5][8];
    {
      const char* hp = hin + (size_t)chunk*PIN;
      if constexpr (IN_FP8){
        uint2 q[5];
        #pragma unroll
        for (int r=0;r<5;r++) q[r] = *reinterpret_cast<const uint2*>(hp + off[r]);
        #pragma unroll
        for (int r=0;r<5;r++) dec8f8(q[r], v[r]);
      } else {
        uint4 q[5];
        #pragma unroll
        for (int r=0;r<5;r++) q[r] = *reinterpret_cast<const uint4*>(hp + off[r]);
        #pragma unroll
        for (int r=0;r<5;r++) unpack8(q[r], v[r]);
      }
    }
    // ---- BN + features ----
    const int cb = chunk*16 + hh*8;
    #pragma unroll
    for (int c=0;c<8;c++){
      const float sc = ss[cb+c], sh = ss[CI+cb+c];
      #pragma unroll
      for (int r=0;r<5;r++) v[r][c] = fmaxf(fmaf(v[r][c], sc, sh), 0.f);
    }
    float y[5][8];
    #pragma unroll
    for (int c=0;c<8;c++){
      y[0][c] = v[0][c];
      y[1][c] = v[1][c] + v[3][c];
      y[2][c] = v[2][c] + v[4][c];
      y[3][c] = fabsf(v[1][c] - v[3][c]);
      y[4][c] = fabsf(v[2][c] - v[4][c]);
    }
    // ---- pack into FB ----
    if constexpr (IN_FP8){
      #pragma unroll
      for (int ks=0; ks<3; ks++){
        char* base = FB + ks*(128*32) + el*32;
        *reinterpret_cast<uint2*>(base + (((0+hh)^t4e)<<3)) = pack8f8(y[2*ks]);
        if (ks < 2){
          *reinterpret_cast<uint2*>(base + (((2+hh)^t4e)<<3)) = pack8f8(y[2*ks+1]);
        } else {
          uint2 zz; zz.x=0u; zz.y=0u;
          *reinterpret_cast<uint2*>(base + (((2+hh)^t4e)<<3)) = zz;
        }
      }
    } else {
      #pragma unroll
      for (int ks=0; ks<3; ks++){
        char* base = FB + ks*8192 + el*64;
        *reinterpret_cast<uint4*>(base + (((0+hh)^t4e)<<4)) = pack8u(y[2*ks]);
        if (ks < 2){
          *reinterpret_cast<uint4*>(base + (((2+hh)^t4e)<<4)) = pack8u(y[2*ks+1]);
        } else {
          const uint4 zz = {0,0,0,0};
          *reinterpret_cast<uint4*>(base + (((2+hh)^t4e)<<4)) = zz;
        }
      }
    }
    __syncthreads();

    // ---- MFMA (B-fragments from global image, L1/L2-hot) ----
    const char* WG = wimg + (size_t)chunk*(3*CO*AB);
    #pragma unroll
    for (int ks=0; ks<3; ks++){
      if constexpr (IN_FP8){
        long long bf[NT];
        #pragma unroll
        for (int n=0;n<NT;n++)
          bf[n] = *reinterpret_cast<const long long*>(WG + ks*(CO*32) + n*512 + col*32 + ((kg^t4c)<<3));
        #pragma unroll
        for (int mt=0;mt<2;mt++){
          const long long af = *reinterpret_cast<const long long*>(
              FB + ks*(128*32) + (wv*32+mt*16+col)*32 + ((kg^t4c)<<3));
          #pragma unroll
          for (int n=0;n<NT;n++)
            acc[mt][n] = __builtin_amdgcn_mfma_f32_16x16x32_fp8_fp8(af, bf[n], acc[mt][n], 0, 0, 0);
        }
      } else {
        short8 bf[NT];
        #pragma unroll
        for (int n=0;n<NT;n++)
          bf[n] = *reinterpret_cast<const short8*>(WG + ks*(CO*64) + n*1024 + col*64 + ((kg^t4c)<<4));
        #pragma unroll
        for (int mt=0;mt<2;mt++){
          const short8 af = *reinterpret_cast<const short8*>(
              FB + ks*8192 + (wv*32+mt*16+col)*64 + ((kg^t4c)<<4));
          #pragma unroll
          for (int n=0;n<NT;n++)
            acc[mt][n] = __builtin_amdgcn_mfma_f32_16x16x32_bf16(af, bf[n], acc[mt][n], 0, 0, 0);
        }
      }
    }
  }

  // ---- per-lane BN-stats partials (registers only) ----
  float sred[2*NT];
  #pragma unroll
  for (int n=0;n<NT;n++){
    float s = 0.f, q2 = 0.f;
    #pragma unroll
    for (int mt=0;mt<2;mt++){
      #pragma unroll
      for (int r=0;r<4;r++){ const float vv = acc[mt][n][r]; s += vv; q2 = fmaf(vv,vv,q2); }
    }
    s  += __shfl_xor(s,16,64);  s  += __shfl_xor(s,32,64);
    q2 += __shfl_xor(q2,16,64); q2 += __shfl_xor(q2,32,64);
    sred[n] = s; sred[NT+n] = q2;
  }

  __syncthreads();
  float* SB = reinterpret_cast<float*>(smem + OBB);   // [4][2*CO]
  if constexpr (OUT_BF16LIN){
    ushort* OB = reinterpret_cast<ushort*>(smem);
    #pragma unroll
    for (int mt=0; mt<2; mt++){
      const int er = wv*32 + mt*16 + 4*kg;
      #pragma unroll
      for (int n=0;n<NT;n++){
        #pragma unroll
        for (int r=0;r<4;r++)
          OB[(er+r)*CO + n*16 + col] = pbf1(acc[mt][n][r]);
      }
    }
  } else {
    uchar* OB = reinterpret_cast<uchar*>(smem);
    #pragma unroll
    for (int mt=0; mt<2; mt++){
      const int er = wv*32 + mt*16 + 4*kg;
      #pragma unroll
      for (int n=0;n<NT;n++){
        #pragma unroll
        for (int r=0;r<4;r++)
          OB[(er+r)*CO + n*16 + col] = f8byte(acc[mt][n][r] * pkf);
      }
    }
  }
  if (kg == 0){
    #pragma unroll
    for (int n=0;n<NT;n++){
      SB[wv*2*CO + n*16 + col]      = sred[n];
      SB[wv*2*CO + CO + n*16 + col] = sred[NT+n];
    }
  }
  __syncthreads();
  if constexpr (OUT_BF16LIN){
    const uint4* src = reinterpret_cast<const uint4*>(smem);
    uint4* dst = reinterpret_cast<uint4*>(hout + (bbase + (size_t)e0)*CO*2);
    constexpr int NV = 128*CO/8;
    for (int i=tid; i<NV; i+=256) dst[i] = src[i];
  } else {
    constexpr int NV = 128*CO/16;     // one uint4 = one 16-ch fp8 plane row
    for (int i=tid; i<NV; i+=256){
      const int pl  = i >> 7;
      const int elx = i & 127;
      const uint4 vv = *reinterpret_cast<const uint4*>(smem + elx*CO + pl*16);
      *reinterpret_cast<uint4*>(hout + (size_t)pl*PB_FP8 + (bbase + (size_t)(e0+elx))*16) = vv;
    }
  }
  if (tid < 2*CO){
    spart[(size_t)bid*2*CO + tid] =
      SB[tid] + SB[2*CO + tid] + SB[4*CO + tid] + SB[6*CO + tid];
  }
}

// ---------------- conv0: CI=5 (padded-8 rows) -> CO=16, VALU ----------------
__launch_bounds__(256)
__global__ void conv0_kernel(const ushort* __restrict__ hin,
                             const int* __restrict__ gemm,
                             const float* __restrict__ w,
                             const float* __restrict__ bias,
                             ushort* __restrict__ hout)
{
  const int bid = blockIdx.x;                     // 2048 = 8 XCD * 256
  const int swz = (bid & 7) * 256 + (bid >> 3);
  const int idx = swz * 256 + threadIdx.x;
  const int b = idx >> 16;
  const int4 g4 = *reinterpret_cast<const int4*>(gemm + (size_t)idx * 4);
  const size_t bbase = (size_t)b << 16;
  float xc[8], n0[8], n1[8], n2[8], n3[8];
  unpack8(*reinterpret_cast<const uint4*>(hin + (size_t)idx*8), xc);
  unpack8(*reinterpret_cast<const uint4*>(hin + (bbase + (size_t)(uint)g4.x)*8), n0);
  unpack8(*reinterpret_cast<const uint4*>(hin + (bbase + (size_t)(uint)g4.y)*8), n1);
  unpack8(*reinterpret_cast<const uint4*>(hin + (bbase + (size_t)(uint)g4.z)*8), n2);
  unpack8(*reinterpret_cast<const uint4*>(hin + (bbase + (size_t)(uint)g4.w)*8), n3);
  float f1[5], f2[5], f3[5], f4[5];
  #pragma unroll
  for (int c=0;c<5;c++){
    f1[c] = n0[c] + n2[c];
    f2[c] = n1[c] + n3[c];
    f3[c] = fabsf(n0[c] - n2[c]);
    f4[c] = fabsf(n1[c] - n3[c]);
  }
  float acc[16];
  #pragma unroll
  for (int o=0;o<16;o++){
    const float* wp = w + (size_t)o*25;
    float a = bias[o];
    #pragma unroll
    for (int c=0;c<5;c++){
      a = fmaf(xc[c], wp[c*5+0], a);
      a = fmaf(f1[c], wp[c*5+1], a);
      a = fmaf(f2[c], wp[c*5+2], a);
      a = fmaf(f3[c], wp[c*5+3], a);
      a = fmaf(f4[c], wp[c*5+4], a);
    }
    acc[o] = a;
  }
  #pragma unroll
  for (int o=0;o<16;o+=8){
    uint4 v;
    v.x = packbf(acc[o+0], acc[o+1]);
    v.y = packbf(acc[o+2], acc[o+3]);
    v.z = packbf(acc[o+4], acc[o+5]);
    v.w = packbf(acc[o+6], acc[o+7]);
    *reinterpret_cast<uint4*>(hout + (size_t)idx * 16 + o) = v;
  }
}

// ---------------- BN stats / merge / finalize / pool / fc --------------
template<int CO>
__launch_bounds__(256)
__global__ void stats_kernel(const ushort* __restrict__ h, float* __restrict__ part)
{
  constexpr int GROUPS = CO / 8;
  constexpr int ROWS   = 256 / GROUPS;
  const int tid = threadIdx.x;
  const int cg  = tid % GROUPS;
  const int row = tid / GROUPS;
  float s[8], q[8];
  #pragma unroll
  for (int i=0;i<8;i++){ s[i]=0.f; q[i]=0.f; }
  for (long idx = (long)blockIdx.x*ROWS + row; idx < BE_TOTAL; idx += (long)gridDim.x*ROWS){
    uint4 v = *reinterpret_cast<const uint4*>(h + (size_t)idx*CO + cg*8);
    float x[8]; unpack8(v, x);
    #pragma unroll
    for (int i=0;i<8;i++){ s[i]+=x[i]; q[i]+=x[i]*x[i]; }
  }
  __shared__ float lds[256*16];
  #pragma unroll
  for (int i=0;i<8;i++){ lds[tid*16+i]=s[i]; lds[tid*16+8+i]=q[i]; }
  __syncthreads();
  if (tid < 2*CO){
    const int st = tid / CO;
    const int c  = tid % CO;
    const int cgg = c >> 3, ci = c & 7;
    float t = 0.f;
    for (int r=0;r<ROWS;r++) t += lds[(r*GROUPS+cgg)*16 + st*8 + ci];
    part[(size_t)blockIdx.x*(2*CO) + tid] = t;
  }
}

template<int CO>
__launch_bounds__(256)
__global__ void merge_stats(const float* __restrict__ in, float* __restrict__ out)
{
  const int t = threadIdx.x;
  if (t >= 2*CO) return;
  const int j = blockIdx.x;            // 128
  float s = 0.f;
  #pragma unroll 4
  for (int r = 0; r < 32; r++) s += in[((size_t)(j*32 + r))*(2*CO) + t];
  out[(size_t)j*(2*CO) + t] = s;
}

// Parallel finalize with accumulator/storage scale folding:
// mean/var computed on acc·Sacc sums (invSa = 1/Sacc); ss applies to values
// stored as SST·true (invSt = 1/SST).
template<int CO>
__launch_bounds__(256)
__global__ void finalize_stats(const float* __restrict__ part, int nblk,
                               const float* __restrict__ g, const float* __restrict__ beta,
                               float invSa, float invSt, float* __restrict__ ss)
{
  constexpr int Q = 256 / CO;
  const int t = threadIdx.x;
  const int c = t % CO;
  const int qq = t / CO;
  float s = 0.f, sq = 0.f;
  for (int b = qq; b < nblk; b += Q){
    s  += part[(size_t)b*2*CO + c];
    sq += part[(size_t)b*2*CO + CO + c];
  }
  __shared__ float lsum[256], lsq[256];
  lsum[t] = s; lsq[t] = sq;
  __syncthreads();
  if (t < CO){
    float ts = 0.f, tq = 0.f;
    #pragma unroll
    for (int r = 0; r < Q; r++){ ts += lsum[r*CO + t]; tq += lsq[r*CO + t]; }
    const float inv = 1.f / (float)BE_TOTAL;
    const float mean = ts * inv * invSa;
    const float var  = tq * inv * invSa * invSa - mean*mean;
    const float scale = g[t] * rsqrtf(var + EPS_BN);
    ss[t]      = scale * invSt;
    ss[CO + t] = beta[t] - mean * scale;
  }
}

__launch_bounds__(256)
__global__ void pool_kernel(const ushort* __restrict__ h3, const float* __restrict__ ss,
                            float* __restrict__ part)
{
  const int tid = threadIdx.x;
  const int cg  = tid % 8;
  const int row = tid / 8;
  const int b   = blockIdx.x >> 6;
  const int blk = blockIdx.x & 63;
  float sc[8], sh[8];
  #pragma unroll
  for (int i=0;i<8;i++){ sc[i]=ss[cg*8+i]; sh[i]=ss[64+cg*8+i]; }
  float s[8];
  #pragma unroll
  for (int i=0;i<8;i++) s[i]=0.f;
  for (int e = blk*32 + row; e < E_DIM; e += 64*32){
    size_t idx = ((size_t)b << 16) + e;
    uint4 v = *reinterpret_cast<const uint4*>(h3 + idx*64 + cg*8);
    float x[8]; unpack8(v, x);
    #pragma unroll
    for (int i=0;i<8;i++) s[i] += fmaxf(fmaf(x[i], sc[i], sh[i]), 0.f);
  }
  __shared__ float lds[256*8];
  #pragma unroll
  for (int i=0;i<8;i++) lds[tid*8+i]=s[i];
  __syncthreads();
  if (tid < 64){
    const int c = tid, cgg = c >> 3, ci = c & 7;
    float t = 0.f;
    for (int r=0;r<32;r++) t += lds[(r*8+cgg)*8 + ci];
    part[((size_t)b*64 + blk)*64 + c] = t;
  }
}

__global__ void finalize_pool(const float* __restrict__ part, float* __restrict__ pooled)
{
  const int t = threadIdx.x;
  const int b = t >> 6, c = t & 63;
  float s = 0.f;
  for (int blk=0;blk<64;blk++) s += part[((size_t)b*64 + blk)*64 + c];
  pooled[t] = s * (1.f / (float)E_DIM);
}

__global__ void fc1_kernel(const float* __restrict__ pooled, const float* __restrict__ dw1,
                           const float* __restrict__ db1, float* __restrict__ h1t)
{
  const int n = blockIdx.x*blockDim.x + threadIdx.x;
  if (n >= 2500) return;
  float acc[8];
  const float bias = db1[n];
  #pragma unroll
  for (int b=0;b<8;b++) acc[b]=bias;
  const float* wr = dw1 + (size_t)n*64;
  #pragma unroll
  for (int c=0;c<64;c++){
    float wv = wr[c];
    #pragma unroll
    for (int b=0;b<8;b++) acc[b] = fmaf(wv, pooled[b*64+c], acc[b]);
  }
  #pragma unroll
  for (int b=0;b<8;b++) h1t[(size_t)n*8 + b] = fmaxf(acc[b], 0.f);
}

__launch_bounds__(256)
__global__ void fc2_kernel(const float* __restrict__ h1t, const float* __restrict__ dw2,
                           const float* __restrict__ db2, const float* __restrict__ oldv,
                           float* __restrict__ out)
{
  const int wv   = threadIdx.x >> 6;
  const int lane = threadIdx.x & 63;
  const int m = blockIdx.x*4 + wv;
  if (m >= 1926) return;
  const float4* wr = reinterpret_cast<const float4*>(dw2 + (size_t)m*2500);
  float acc[8];
  #pragma unroll
  for (int b=0;b<8;b++) acc[b]=0.f;
  for (int j = lane; j < 625; j += 64){
    const float4 w4 = wr[j];
    const float4* hp = reinterpret_cast<const float4*>(h1t + (size_t)j*32);
    const float4 h0a = hp[0], h0b = hp[1];
    const float4 h1a = hp[2], h1b = hp[3];
    const float4 h2a = hp[4], h2b = hp[5];
    const float4 h3a = hp[6], h3b = hp[7];
    acc[0] = fmaf(w4.x, h0a.x, fmaf(w4.y, h1a.x, fmaf(w4.z, h2a.x, fmaf(w4.w, h3a.x, acc[0]))));
    acc[1] = fmaf(w4.x, h0a.y, fmaf(w4.y, h1a.y, fmaf(w4.z, h2a.y, fmaf(w4.w, h3a.y, acc[1]))));
    acc[2] = fmaf(w4.x, h0a.z, fmaf(w4.y, h1a.z, fmaf(w4.z, h2a.z, fmaf(w4.w, h3a.z, acc[2]))));
    acc[3] = fmaf(w4.x, h0a.w, fmaf(w4.y, h1a.w, fmaf(w4.z, h2a.w, fmaf(w4.w, h3a.w, acc[3]))));
    acc[4] = fmaf(w4.x, h0b.x, fmaf(w4.y, h1b.x, fmaf(w4.z, h2b.x, fmaf(w4.w, h3b.x, acc[4]))));
    acc[5] = fmaf(w4.x, h0b.y, fmaf(w4.y, h1b.y, fmaf(w4.z, h2b.y, fmaf(w4.w, h3b.y, acc[5]))));
    acc[6] = fmaf(w4.x, h0b.z, fmaf(w4.y, h1b.z, fmaf(w4.z, h2b.z, fmaf(w4.w, h3b.z, acc[6]))));
    acc[7] = fmaf(w4.x, h0b.w, fmaf(w4.y, h1b.w, fmaf(w4.z, h2b.w, fmaf(w4.w, h3b.w, acc[7]))));
  }
  #pragma unroll
  for (int s=1; s<64; s<<=1){
    #pragma unroll
    for (int b=0;b<8;b++) acc[b] += __shfl_xor(acc[b], s, 64);
  }
  if (lane == 0){
    const float bm = db2[m];
    #pragma unroll
    for (int b=0;b<8;b++){
      const int t = b*1926 + m;
      out[t] = acc[b] + bm + oldv[t];
    }
  }
}

__launch_bounds__(256)
__global__ void transpose_x(const float* __restrict__ x, ushort* __restrict__ xt)
{
  const int idx = blockIdx.x*256 + threadIdx.x;
  const int b = idx >> 16, e = idx & 65535;
  const float* xb = x + (size_t)b*5*E_DIM + e;
  uint4 v;
  v.x = packbf(xb[0],               xb[(size_t)E_DIM]);
  v.y = packbf(xb[2*(size_t)E_DIM], xb[3*(size_t)E_DIM]);
  v.z = packbf(xb[4*(size_t)E_DIM], 0.f);
  v.w = 0u;
  *reinterpret_cast<uint4*>(xt + (size_t)idx*8) = v;
}

extern "C" void kernel_launch(void* const* d_in, const int* in_sizes, int n_in,
                              void* d_out, int out_size, void* d_ws, size_t ws_size,
                              hipStream_t stream)
{
  const float* x    = (const float*)d_in[0];
  const int*   gm   = (const int*)d_in[1];
  const float* oldv = (const float*)d_in[2];
  const float* w0 = (const float*)d_in[3],  *b0 = (const float*)d_in[4];
  const float* g0 = (const float*)d_in[5],  *be0= (const float*)d_in[6];
  const float* w1 = (const float*)d_in[7],  *b1 = (const float*)d_in[8];
  const float* g1 = (const float*)d_in[9],  *be1= (const float*)d_in[10];
  const float* w2 = (const float*)d_in[11], *b2 = (const float*)d_in[12];
  const float* g2 = (const float*)d_in[13], *be2= (const float*)d_in[14];
  const float* w3 = (const float*)d_in[15], *b3 = (const float*)d_in[16];
  const float* g3 = (const float*)d_in[17], *be3= (const float*)d_in[18];
  const float* dw1 = (const float*)d_in[19], *db1 = (const float*)d_in[20];
  const float* dw2 = (const float*)d_in[21], *db2 = (const float*)d_in[22];

  char* ws = (char*)d_ws;
  size_t off = 0;
  auto alloc = [&](size_t n){ size_t o = off; off += (n + 255) & ~(size_t)255; return o; };
  ushort* xt = (ushort*)(ws + alloc((size_t)BE_TOTAL*8*2));
  ushort* h0 = (ushort*)(ws + alloc((size_t)BE_TOTAL*16*2));
  char*   h1 = (char*)  (ws + alloc((size_t)BE_TOTAL*32));   // 2 fp8 planes
  char*   h2 = (char*)  (ws + alloc((size_t)BE_TOTAL*64));   // 4 fp8 planes
  ushort* h3 = (ushort*)(ws + alloc((size_t)BE_TOTAL*64*2)); // bf16 linear
  float* part   = (float*)(ws + alloc((size_t)NB_STATS*128*4));
  float* spart  = (float*)(ws + alloc((size_t)4096*128*4));
  float* mpart  = (float*)(ws + alloc((size_t)128*128*4));
  float* ss0    = (float*)(ws + alloc(512));
  float* ss1    = (float*)(ws + alloc(512));
  float* ss2    = (float*)(ws + alloc(512));
  float* ss3    = (float*)(ws + alloc(512));
  float* ppart  = (float*)(ws + alloc((size_t)8*64*64*4));
  float* pooled = (float*)(ws + alloc(512*4));
  float* h1fc   = (float*)(ws + alloc(20000*4));
  ushort* w1i   = (ushort*)(ws + alloc((size_t)3*32*32*2));
  uchar*  w2i   = (uchar*) (ws + alloc((size_t)6*64*32));
  uchar*  w3i   = (uchar*) (ws + alloc((size_t)12*64*32));
  (void)ws_size; (void)in_sizes; (void)n_in; (void)out_size;

  const int CB = BE_TOTAL/256;   // 2048
  const int MB = BE_TOTAL/128;   // 4096

  transpose_x<<<CB,256,0,stream>>>(x, xt);
  wprep<16,32><<<2,256,0,stream>>>(w1, w1i);
  wprep8<32,64><<<6,256,0,stream>>>(w2, w2i);
  wprep8<64,64><<<12,256,0,stream>>>(w3, w3i);

  conv0_kernel<<<CB,256,0,stream>>>(xt, gm, w0, b0, h0);
  stats_kernel<16><<<NB_STATS,256,0,stream>>>(h0, part);
  finalize_stats<16><<<1,256,0,stream>>>(part, NB_STATS, g0, be0, 1.f, 1.f, ss0);

  // L1: bf16 in (h0), bf16 MFMA, fp8 out (stored = 16*true)
  mconv_mfma<16,32,false,false><<<MB,256,0,stream>>>(
      (const char*)h0, gm, (const char*)w1i, b1, 1.f, ss0, 16.f, h1, spart);
  merge_stats<32><<<128,256,0,stream>>>(spart, mpart);
  finalize_stats<32><<<1,256,0,stream>>>(mpart, 128, g1, be1, 1.f, 1.f/16.f, ss1);

  // L2: fp8 in (h1), fp8 MFMA (acc = 64*true), fp8 out (stored = 16*true)
  mconv_mfma<32,64,true,false><<<MB,256,0,stream>>>(
      h1, gm, (const char*)w2i, b2, 64.f, ss1, 0.25f, h2, spart);
  merge_stats<64><<<128,256,0,stream>>>(spart, mpart);
  finalize_stats<64><<<1,256,0,stream>>>(mpart, 128, g2, be2, 1.f/64.f, 1.f/16.f, ss2);

  // L3: fp8 in (h2), fp8 MFMA (acc = 64*true), bf16 linear out (stored = 64*true)
  mconv_mfma<64,64,true,true><<<MB,256,0,stream>>>(
      h2, gm, (const char*)w3i, b3, 64.f, ss2, 1.f, (char*)h3, spart);
  merge_stats<64><<<128,256,0,stream>>>(spart, mpart);
  finalize_stats<64><<<1,256,0,stream>>>(mpart, 128, g3, be3, 1.f/64.f, 1.f/64.f, ss3);

  pool_kernel<<<512,256,0,stream>>>(h3, ss3, ppart);
  finalize_pool<<<1,512,0,stream>>>(ppart, pooled);
  fc1_kernel<<<10,256,0,stream>>>(pooled, dw1, db1, h1fc);
  fc2_kernel<<<482,256,0,stream>>>(h1fc, dw2, db2, oldv, (float*)d_out);
}

// Round 12
// 248.641 us; speedup vs baseline: 1.2523x; 1.0137x over previous
//
#include <hip/hip_runtime.h>

#define E_DIM 65536
#define BE_TOTAL 524288
#define EPS_BN 1e-5f
#define NB_STATS 256

typedef unsigned int uint;
typedef unsigned short ushort;
typedef unsigned char uchar;
typedef __attribute__((ext_vector_type(8))) short short8;   // 8 bf16 (4 VGPR)
typedef __attribute__((ext_vector_type(4))) float floatx4;

#define PB_FP8 ((size_t)BE_TOTAL*16)   // bytes per 16-ch fp8 plane

__device__ __forceinline__ float bflo(uint u){ return __uint_as_float(u << 16); }
__device__ __forceinline__ float bfhi(uint u){ return __uint_as_float(u & 0xffff0000u); }

__device__ __forceinline__ ushort pbf1(float a){
  uint ua = __float_as_uint(a);
  return (ushort)((ua + 0x7fffu + ((ua >> 16) & 1u)) >> 16);
}
__device__ __forceinline__ uint packbf(float a, float b){
  return (uint)pbf1(a) | ((uint)pbf1(b) << 16);
}
__device__ __forceinline__ void unpack8(uint4 v, float* x){
  x[0]=bflo(v.x); x[1]=bfhi(v.x); x[2]=bflo(v.y); x[3]=bfhi(v.y);
  x[4]=bflo(v.z); x[5]=bfhi(v.z); x[6]=bflo(v.w); x[7]=bfhi(v.w);
}
__device__ __forceinline__ uint4 pack8u(const float* z){
  uint4 v;
  v.x = packbf(z[0],z[1]); v.y = packbf(z[2],z[3]);
  v.z = packbf(z[4],z[5]); v.w = packbf(z[6],z[7]);
  return v;
}

// ---- fp8 e4m3 helpers ----
__device__ __forceinline__ uint2 pack8f8(const float* z){
  int lo = __builtin_amdgcn_cvt_pk_fp8_f32(z[0], z[1], 0,  false);
  lo     = __builtin_amdgcn_cvt_pk_fp8_f32(z[2], z[3], lo, true);
  int hi = __builtin_amdgcn_cvt_pk_fp8_f32(z[4], z[5], 0,  false);
  hi     = __builtin_amdgcn_cvt_pk_fp8_f32(z[6], z[7], hi, true);
  uint2 r; r.x = (uint)lo; r.y = (uint)hi; return r;
}
__device__ __forceinline__ void dec8f8(uint2 w, float* x){
  x[0]=__builtin_amdgcn_cvt_f32_fp8((int)w.x,0);
  x[1]=__builtin_amdgcn_cvt_f32_fp8((int)w.x,1);
  x[2]=__builtin_amdgcn_cvt_f32_fp8((int)w.x,2);
  x[3]=__builtin_amdgcn_cvt_f32_fp8((int)w.x,3);
  x[4]=__builtin_amdgcn_cvt_f32_fp8((int)w.y,0);
  x[5]=__builtin_amdgcn_cvt_f32_fp8((int)w.y,1);
  x[6]=__builtin_amdgcn_cvt_f32_fp8((int)w.y,2);
  x[7]=__builtin_amdgcn_cvt_f32_fp8((int)w.y,3);
}
__device__ __forceinline__ uchar f8byte(float v){
  return (uchar)(__builtin_amdgcn_cvt_pk_fp8_f32(v, 0.f, 0, false) & 0xff);
}

// ------------- weight relayout (bf16 image, layer1): 16-ch chunks, KSTEPS=3 ----
template<int CI, int CO>
__global__ void wprep(const float* __restrict__ w, ushort* __restrict__ img)
{
  constexpr int CHUNKS = CI/16;
  const int t = blockIdx.x*256 + threadIdx.x;
  if (t >= CHUNKS*3*CO*4) return;
  const int s  = t & 3;
  const int o  = (t >> 2) % CO;
  const int ck = (t >> 2) / CO;
  const int chunk = ck / 3;
  const int ks    = ck % 3;
  float z[8];
  #pragma unroll
  for (int j8=0;j8<8;j8++){
    const int j = s*8 + j8;
    const int ft = ks*2 + (j>>4);
    const int ci = chunk*16 + (j & 15);
    z[j8] = (ft < 5) ? w[((size_t)o*CI + ci)*5 + ft] : 0.f;
  }
  const int t4 = (o&3) ^ ((o>>2)&3);
  *reinterpret_cast<uint4*>(img + ((size_t)(ck*CO + o))*32 + ((s^t4)<<3)) = pack8u(z);
}

// ------------- weight relayout (fp8 image, layers 2/3): rows 32B, groups 8B ----
template<int CI, int CO>
__global__ void wprep8(const float* __restrict__ w, uchar* __restrict__ img)
{
  constexpr int CHUNKS = CI/16;
  const int t = blockIdx.x*256 + threadIdx.x;
  if (t >= CHUNKS*3*CO*4) return;
  const int g  = t & 3;
  const int o  = (t >> 2) % CO;
  const int ck = (t >> 2) / CO;
  const int chunk = ck / 3;
  const int ks    = ck % 3;
  float z[8];
  #pragma unroll
  for (int j8=0;j8<8;j8++){
    const int j = g*8 + j8;
    const int ft = ks*2 + (j>>4);
    const int ci = chunk*16 + (j & 15);
    z[j8] = (ft < 5) ? w[((size_t)o*CI + ci)*5 + ft] * 64.f : 0.f;   // SW=64
  }
  const int t4 = (o&3) ^ ((o>>2)&3);
  *reinterpret_cast<uint2*>(img + ((size_t)(ck*CO + o))*32 + ((g^t4)<<3)) = pack8f8(z);
}

// ---------------- MFMA mesh-conv (fused BN-stats epilogue) ----------------
// Input: CI/16 planes, bf16 (32B rows) or fp8 (16B rows). Output: fp8 planes
// or bf16 linear. F in LDS, double-buffered when CHUNKS>1: per phase
// {issue next gather, MFMA(cur), build next, one barrier}.
template<int CI, int CO, bool IN_FP8, bool OUT_BF16LIN>
__launch_bounds__(256, 4)
__global__ void mconv_mfma(const char* __restrict__ hin,
                           const int* __restrict__ gemm,
                           const char* __restrict__ wimg,
                           const float* __restrict__ bias, float bscale,
                           const float* __restrict__ ss, float pkf,
                           char* __restrict__ hout,
                           float* __restrict__ spart)
{
  constexpr int CHUNKS = CI/16;
  constexpr int NT = CO/16;
  constexpr int AB  = IN_FP8 ? 32 : 64;               // FB row bytes
  constexpr int FBY = 3*128*AB;
  constexpr int NBUF = (CHUNKS > 1) ? 2 : 1;
  constexpr int OBB = 128*CO*(OUT_BF16LIN?2:1);
  constexpr int SBY = 4*2*CO*4;
  constexpr int SMEM = (NBUF*FBY > OBB+SBY) ? NBUF*FBY : (OBB+SBY);
  constexpr size_t PIN = IN_FP8 ? PB_FP8 : (size_t)BE_TOTAL*32;
  constexpr int RB = IN_FP8 ? 16 : 32;                // input row bytes
  __shared__ char smem[SMEM];
  char* FB = smem;

  const int tid = threadIdx.x;
  const int bid = blockIdx.x;            // 4096 = 8 (batch=XCD) * 512
  const int b   = bid & 7;
  const int e0  = (bid >> 3) * 128;
  const size_t bbase = (size_t)b << 16;

  const int lane = tid & 63;
  const int wv   = tid >> 6;
  const int col  = lane & 15;
  const int kg   = lane >> 4;
  const int t4c  = (col & 3) ^ ((col >> 2) & 3);

  floatx4 acc[2][NT];
  #pragma unroll
  for (int n=0;n<NT;n++){
    const float bv = bias[n*16 + col] * bscale;
    #pragma unroll
    for (int mt=0;mt<2;mt++) acc[mt][n] = (floatx4){bv,bv,bv,bv};
  }

  // gather byte-offsets within a plane: 2 threads/element, hh = 8-ch half
  const int el = tid >> 1;
  const int hh = tid & 1;
  const int t4e = (el&3) ^ ((el>>2)&3);
  uint off[5];
  {
    const size_t idx = bbase + (size_t)(e0 + el);
    const int4 g4 = *reinterpret_cast<const int4*>(gemm + idx*4);
    off[0] = (uint)(idx*RB + hh*(RB/2));
    off[1] = (uint)((bbase + (size_t)(uint)g4.x)*RB + hh*(RB/2));
    off[2] = (uint)((bbase + (size_t)(uint)g4.y)*RB + hh*(RB/2));
    off[3] = (uint)((bbase + (size_t)(uint)g4.z)*RB + hh*(RB/2));
    off[4] = (uint)((bbase + (size_t)(uint)g4.w)*RB + hh*(RB/2));
  }

  // BN + features + pack into FB buffer (v[5][8] already decoded)
  auto BUILD = [&](float (&v)[5][8], int chunk, char* FBb){
    const int cb = chunk*16 + hh*8;
    #pragma unroll
    for (int c=0;c<8;c++){
      const float sc = ss[cb+c], sh = ss[CI+cb+c];
      #pragma unroll
      for (int r=0;r<5;r++) v[r][c] = fmaxf(fmaf(v[r][c], sc, sh), 0.f);
    }
    float y[5][8];
    #pragma unroll
    for (int c=0;c<8;c++){
      y[0][c] = v[0][c];
      y[1][c] = v[1][c] + v[3][c];
      y[2][c] = v[2][c] + v[4][c];
      y[3][c] = fabsf(v[1][c] - v[3][c]);
      y[4][c] = fabsf(v[2][c] - v[4][c]);
    }
    if constexpr (IN_FP8){
      #pragma unroll
      for (int ks=0; ks<3; ks++){
        char* base = FBb + ks*(128*32) + el*32;
        *reinterpret_cast<uint2*>(base + (((0+hh)^t4e)<<3)) = pack8f8(y[2*ks]);
        if (ks < 2){
          *reinterpret_cast<uint2*>(base + (((2+hh)^t4e)<<3)) = pack8f8(y[2*ks+1]);
        } else {
          uint2 zz; zz.x=0u; zz.y=0u;
          *reinterpret_cast<uint2*>(base + (((2+hh)^t4e)<<3)) = zz;
        }
      }
    } else {
      #pragma unroll
      for (int ks=0; ks<3; ks++){
        char* base = FBb + ks*8192 + el*64;
        *reinterpret_cast<uint4*>(base + (((0+hh)^t4e)<<4)) = pack8u(y[2*ks]);
        if (ks < 2){
          *reinterpret_cast<uint4*>(base + (((2+hh)^t4e)<<4)) = pack8u(y[2*ks+1]);
        } else {
          const uint4 zz = {0,0,0,0};
          *reinterpret_cast<uint4*>(base + (((2+hh)^t4e)<<4)) = zz;
        }
      }
    }
  };

  auto MMA = [&](int chunk, const char* FBb){
    const char* WG = wimg + (size_t)chunk*(3*CO*AB);
    #pragma unroll
    for (int ks=0; ks<3; ks++){
      if constexpr (IN_FP8){
        long long bf[NT];
        #pragma unroll
        for (int n=0;n<NT;n++)
          bf[n] = *reinterpret_cast<const long long*>(WG + ks*(CO*32) + n*512 + col*32 + ((kg^t4c)<<3));
        #pragma unroll
        for (int mt=0;mt<2;mt++){
          const long long af = *reinterpret_cast<const long long*>(
              FBb + ks*(128*32) + (wv*32+mt*16+col)*32 + ((kg^t4c)<<3));
          #pragma unroll
          for (int n=0;n<NT;n++)
            acc[mt][n] = __builtin_amdgcn_mfma_f32_16x16x32_fp8_fp8(af, bf[n], acc[mt][n], 0, 0, 0);
        }
      } else {
        short8 bf[NT];
        #pragma unroll
        for (int n=0;n<NT;n++)
          bf[n] = *reinterpret_cast<const short8*>(WG + ks*(CO*64) + n*1024 + col*64 + ((kg^t4c)<<4));
        #pragma unroll
        for (int mt=0;mt<2;mt++){
          const short8 af = *reinterpret_cast<const short8*>(
              FBb + ks*8192 + (wv*32+mt*16+col)*64 + ((kg^t4c)<<4));
          #pragma unroll
          for (int n=0;n<NT;n++)
            acc[mt][n] = __builtin_amdgcn_mfma_f32_16x16x32_bf16(af, bf[n], acc[mt][n], 0, 0, 0);
        }
      }
    }
  };

  if constexpr (CHUNKS == 1){
    float v[5][8];
    if constexpr (IN_FP8){
      uint2 q[5];
      #pragma unroll
      for (int r=0;r<5;r++) q[r] = *reinterpret_cast<const uint2*>(hin + off[r]);
      #pragma unroll
      for (int r=0;r<5;r++) dec8f8(q[r], v[r]);
    } else {
      uint4 q[5];
      #pragma unroll
      for (int r=0;r<5;r++) q[r] = *reinterpret_cast<const uint4*>(hin + off[r]);
      #pragma unroll
      for (int r=0;r<5;r++) unpack8(q[r], v[r]);
    }
    BUILD(v, 0, FB);
    __syncthreads();
    MMA(0, FB);
  } else {
    // pipelined: fp8-input only (CI=32/64)
    {
      uint2 q[5];
      #pragma unroll
      for (int r=0;r<5;r++) q[r] = *reinterpret_cast<const uint2*>(hin + off[r]);
      float v[5][8];
      #pragma unroll
      for (int r=0;r<5;r++) dec8f8(q[r], v[r]);
      BUILD(v, 0, FB);
    }
    __syncthreads();
    #pragma unroll
    for (int c=0; c<CHUNKS; ++c){
      uint2 qn[5];
      if (c+1 < CHUNKS){
        const char* hp = hin + (size_t)(c+1)*PIN;
        #pragma unroll
        for (int r=0;r<5;r++) qn[r] = *reinterpret_cast<const uint2*>(hp + off[r]);
      }
      MMA(c, FB + (c&1)*FBY);
      if (c+1 < CHUNKS){
        float v[5][8];
        #pragma unroll
        for (int r=0;r<5;r++) dec8f8(qn[r], v[r]);
        BUILD(v, c+1, FB + ((c+1)&1)*FBY);
        __syncthreads();
      }
    }
  }

  // ---- per-lane BN-stats partials (registers only) ----
  float sred[2*NT];
  #pragma unroll
  for (int n=0;n<NT;n++){
    float s = 0.f, q2 = 0.f;
    #pragma unroll
    for (int mt=0;mt<2;mt++){
      #pragma unroll
      for (int r=0;r<4;r++){ const float vv = acc[mt][n][r]; s += vv; q2 = fmaf(vv,vv,q2); }
    }
    s  += __shfl_xor(s,16,64);  s  += __shfl_xor(s,32,64);
    q2 += __shfl_xor(q2,16,64); q2 += __shfl_xor(q2,32,64);
    sred[n] = s; sred[NT+n] = q2;
  }

  __syncthreads();
  float* SB = reinterpret_cast<float*>(smem + OBB);   // [4][2*CO]
  if constexpr (OUT_BF16LIN){
    ushort* OB = reinterpret_cast<ushort*>(smem);
    #pragma unroll
    for (int mt=0; mt<2; mt++){
      const int er = wv*32 + mt*16 + 4*kg;
      #pragma unroll
      for (int n=0;n<NT;n++){
        #pragma unroll
        for (int r=0;r<4;r++)
          OB[(er+r)*CO + n*16 + col] = pbf1(acc[mt][n][r]);
      }
    }
  } else {
    uchar* OB = reinterpret_cast<uchar*>(smem);
    #pragma unroll
    for (int mt=0; mt<2; mt++){
      const int er = wv*32 + mt*16 + 4*kg;
      #pragma unroll
      for (int n=0;n<NT;n++){
        #pragma unroll
        for (int r=0;r<4;r++)
          OB[(er+r)*CO + n*16 + col] = f8byte(acc[mt][n][r] * pkf);
      }
    }
  }
  if (kg == 0){
    #pragma unroll
    for (int n=0;n<NT;n++){
      SB[wv*2*CO + n*16 + col]      = sred[n];
      SB[wv*2*CO + CO + n*16 + col] = sred[NT+n];
    }
  }
  __syncthreads();
  if constexpr (OUT_BF16LIN){
    const uint4* src = reinterpret_cast<const uint4*>(smem);
    uint4* dst = reinterpret_cast<uint4*>(hout + (bbase + (size_t)e0)*CO*2);
    constexpr int NV = 128*CO/8;
    for (int i=tid; i<NV; i+=256) dst[i] = src[i];
  } else {
    constexpr int NV = 128*CO/16;     // one uint4 = one 16-ch fp8 plane row
    for (int i=tid; i<NV; i+=256){
      const int pl  = i >> 7;
      const int elx = i & 127;
      const uint4 vv = *reinterpret_cast<const uint4*>(smem + elx*CO + pl*16);
      *reinterpret_cast<uint4*>(hout + (size_t)pl*PB_FP8 + (bbase + (size_t)(e0+elx))*16) = vv;
    }
  }
  if (tid < 2*CO){
    spart[(size_t)bid*2*CO + tid] =
      SB[tid] + SB[2*CO + tid] + SB[4*CO + tid] + SB[6*CO + tid];
  }
}

// ---------------- conv0: CI=5 (padded-8 rows) -> CO=16, VALU ----------------
__launch_bounds__(256)
__global__ void conv0_kernel(const ushort* __restrict__ hin,
                             const int* __restrict__ gemm,
                             const float* __restrict__ w,
                             const float* __restrict__ bias,
                             ushort* __restrict__ hout)
{
  const int bid = blockIdx.x;                     // 2048 = 8 XCD * 256
  const int swz = (bid & 7) * 256 + (bid >> 3);
  const int idx = swz * 256 + threadIdx.x;
  const int b = idx >> 16;
  const int4 g4 = *reinterpret_cast<const int4*>(gemm + (size_t)idx * 4);
  const size_t bbase = (size_t)b << 16;
  float xc[8], n0[8], n1[8], n2[8], n3[8];
  unpack8(*reinterpret_cast<const uint4*>(hin + (size_t)idx*8), xc);
  unpack8(*reinterpret_cast<const uint4*>(hin + (bbase + (size_t)(uint)g4.x)*8), n0);
  unpack8(*reinterpret_cast<const uint4*>(hin + (bbase + (size_t)(uint)g4.y)*8), n1);
  unpack8(*reinterpret_cast<const uint4*>(hin + (bbase + (size_t)(uint)g4.z)*8), n2);
  unpack8(*reinterpret_cast<const uint4*>(hin + (bbase + (size_t)(uint)g4.w)*8), n3);
  float f1[5], f2[5], f3[5], f4[5];
  #pragma unroll
  for (int c=0;c<5;c++){
    f1[c] = n0[c] + n2[c];
    f2[c] = n1[c] + n3[c];
    f3[c] = fabsf(n0[c] - n2[c]);
    f4[c] = fabsf(n1[c] - n3[c]);
  }
  float acc[16];
  #pragma unroll
  for (int o=0;o<16;o++){
    const float* wp = w + (size_t)o*25;
    float a = bias[o];
    #pragma unroll
    for (int c=0;c<5;c++){
      a = fmaf(xc[c], wp[c*5+0], a);
      a = fmaf(f1[c], wp[c*5+1], a);
      a = fmaf(f2[c], wp[c*5+2], a);
      a = fmaf(f3[c], wp[c*5+3], a);
      a = fmaf(f4[c], wp[c*5+4], a);
    }
    acc[o] = a;
  }
  #pragma unroll
  for (int o=0;o<16;o+=8){
    uint4 v;
    v.x = packbf(acc[o+0], acc[o+1]);
    v.y = packbf(acc[o+2], acc[o+3]);
    v.z = packbf(acc[o+4], acc[o+5]);
    v.w = packbf(acc[o+6], acc[o+7]);
    *reinterpret_cast<uint4*>(hout + (size_t)idx * 16 + o) = v;
  }
}

// ---------------- BN stats / merge / finalize / pool / fc --------------
template<int CO>
__launch_bounds__(256)
__global__ void stats_kernel(const ushort* __restrict__ h, float* __restrict__ part)
{
  constexpr int GROUPS = CO / 8;
  constexpr int ROWS   = 256 / GROUPS;
  const int tid = threadIdx.x;
  const int cg  = tid % GROUPS;
  const int row = tid / GROUPS;
  float s[8], q[8];
  #pragma unroll
  for (int i=0;i<8;i++){ s[i]=0.f; q[i]=0.f; }
  for (long idx = (long)blockIdx.x*ROWS + row; idx < BE_TOTAL; idx += (long)gridDim.x*ROWS){
    uint4 v = *reinterpret_cast<const uint4*>(h + (size_t)idx*CO + cg*8);
    float x[8]; unpack8(v, x);
    #pragma unroll
    for (int i=0;i<8;i++){ s[i]+=x[i]; q[i]+=x[i]*x[i]; }
  }
  __shared__ float lds[256*16];
  #pragma unroll
  for (int i=0;i<8;i++){ lds[tid*16+i]=s[i]; lds[tid*16+8+i]=q[i]; }
  __syncthreads();
  if (tid < 2*CO){
    const int st = tid / CO;
    const int c  = tid % CO;
    const int cgg = c >> 3, ci = c & 7;
    float t = 0.f;
    for (int r=0;r<ROWS;r++) t += lds[(r*GROUPS+cgg)*16 + st*8 + ci];
    part[(size_t)blockIdx.x*(2*CO) + tid] = t;
  }
}

template<int CO>
__launch_bounds__(256)
__global__ void merge_stats(const float* __restrict__ in, float* __restrict__ out)
{
  const int t = threadIdx.x;
  if (t >= 2*CO) return;
  const int j = blockIdx.x;            // 128
  float s = 0.f;
  #pragma unroll 4
  for (int r = 0; r < 32; r++) s += in[((size_t)(j*32 + r))*(2*CO) + t];
  out[(size_t)j*(2*CO) + t] = s;
}

// Parallel finalize with accumulator/storage scale folding.
template<int CO>
__launch_bounds__(256)
__global__ void finalize_stats(const float* __restrict__ part, int nblk,
                               const float* __restrict__ g, const float* __restrict__ beta,
                               float invSa, float invSt, float* __restrict__ ss)
{
  constexpr int Q = 256 / CO;
  const int t = threadIdx.x;
  const int c = t % CO;
  const int qq = t / CO;
  float s = 0.f, sq = 0.f;
  for (int b = qq; b < nblk; b += Q){
    s  += part[(size_t)b*2*CO + c];
    sq += part[(size_t)b*2*CO + CO + c];
  }
  __shared__ float lsum[256], lsq[256];
  lsum[t] = s; lsq[t] = sq;
  __syncthreads();
  if (t < CO){
    float ts = 0.f, tq = 0.f;
    #pragma unroll
    for (int r = 0; r < Q; r++){ ts += lsum[r*CO + t]; tq += lsq[r*CO + t]; }
    const float inv = 1.f / (float)BE_TOTAL;
    const float mean = ts * inv * invSa;
    const float var  = tq * inv * invSa * invSa - mean*mean;
    const float scale = g[t] * rsqrtf(var + EPS_BN);
    ss[t]      = scale * invSt;
    ss[CO + t] = beta[t] - mean * scale;
  }
}

// pool over fp8 planes: h3 = 4 planes of [b][e][16] fp8 (stored = 16*true,
// invSt folded into ss)
__launch_bounds__(256)
__global__ void pool_kernel(const char* __restrict__ h3, const float* __restrict__ ss,
                            float* __restrict__ part)
{
  const int tid = threadIdx.x;
  const int cg  = tid % 8;          // 8-ch group: plane cg>>1, half cg&1
  const int row = tid / 8;
  const int b   = blockIdx.x >> 6;
  const int blk = blockIdx.x & 63;
  float sc[8], sh[8];
  #pragma unroll
  for (int i=0;i<8;i++){ sc[i]=ss[cg*8+i]; sh[i]=ss[64+cg*8+i]; }
  float s[8];
  #pragma unroll
  for (int i=0;i<8;i++) s[i]=0.f;
  const char* hp = h3 + (size_t)(cg>>1)*PB_FP8 + (cg&1)*8;
  for (int e = blk*32 + row; e < E_DIM; e += 64*32){
    size_t idx = ((size_t)b << 16) + e;
    uint2 v = *reinterpret_cast<const uint2*>(hp + idx*16);
    float x[8]; dec8f8(v, x);
    #pragma unroll
    for (int i=0;i<8;i++) s[i] += fmaxf(fmaf(x[i], sc[i], sh[i]), 0.f);
  }
  __shared__ float lds[256*8];
  #pragma unroll
  for (int i=0;i<8;i++) lds[tid*8+i]=s[i];
  __syncthreads();
  if (tid < 64){
    const int c = tid, cgg = c >> 3, ci = c & 7;
    float t = 0.f;
    for (int r=0;r<32;r++) t += lds[(r*8+cgg)*8 + ci];
    part[((size_t)b*64 + blk)*64 + c] = t;
  }
}

__global__ void finalize_pool(const float* __restrict__ part, float* __restrict__ pooled)
{
  const int t = threadIdx.x;
  const int b = t >> 6, c = t & 63;
  float s = 0.f;
  for (int blk=0;blk<64;blk++) s += part[((size_t)b*64 + blk)*64 + c];
  pooled[t] = s * (1.f / (float)E_DIM);
}

__global__ void fc1_kernel(const float* __restrict__ pooled, const float* __restrict__ dw1,
                           const float* __restrict__ db1, float* __restrict__ h1t)
{
  const int n = blockIdx.x*blockDim.x + threadIdx.x;
  if (n >= 2500) return;
  float acc[8];
  const float bias = db1[n];
  #pragma unroll
  for (int b=0;b<8;b++) acc[b]=bias;
  const float* wr = dw1 + (size_t)n*64;
  #pragma unroll
  for (int c=0;c<64;c++){
    float wv = wr[c];
    #pragma unroll
    for (int b=0;b<8;b++) acc[b] = fmaf(wv, pooled[b*64+c], acc[b]);
  }
  #pragma unroll
  for (int b=0;b<8;b++) h1t[(size_t)n*8 + b] = fmaxf(acc[b], 0.f);
}

__launch_bounds__(256)
__global__ void fc2_kernel(const float* __restrict__ h1t, const float* __restrict__ dw2,
                           const float* __restrict__ db2, const float* __restrict__ oldv,
                           float* __restrict__ out)
{
  const int wv   = threadIdx.x >> 6;
  const int lane = threadIdx.x & 63;
  const int m = blockIdx.x*4 + wv;
  if (m >= 1926) return;
  const float4* wr = reinterpret_cast<const float4*>(dw2 + (size_t)m*2500);
  float acc[8];
  #pragma unroll
  for (int b=0;b<8;b++) acc[b]=0.f;
  for (int j = lane; j < 625; j += 64){
    const float4 w4 = wr[j];
    const float4* hp = reinterpret_cast<const float4*>(h1t + (size_t)j*32);
    const float4 h0a = hp[0], h0b = hp[1];
    const float4 h1a = hp[2], h1b = hp[3];
    const float4 h2a = hp[4], h2b = hp[5];
    const float4 h3a = hp[6], h3b = hp[7];
    acc[0] = fmaf(w4.x, h0a.x, fmaf(w4.y, h1a.x, fmaf(w4.z, h2a.x, fmaf(w4.w, h3a.x, acc[0]))));
    acc[1] = fmaf(w4.x, h0a.y, fmaf(w4.y, h1a.y, fmaf(w4.z, h2a.y, fmaf(w4.w, h3a.y, acc[1]))));
    acc[2] = fmaf(w4.x, h0a.z, fmaf(w4.y, h1a.z, fmaf(w4.z, h2a.z, fmaf(w4.w, h3a.z, acc[2]))));
    acc[3] = fmaf(w4.x, h0a.w, fmaf(w4.y, h1a.w, fmaf(w4.z, h2a.w, fmaf(w4.w, h3a.w, acc[3]))));
    acc[4] = fmaf(w4.x, h0b.x, fmaf(w4.y, h1b.x, fmaf(w4.z, h2b.x, fmaf(w4.w, h3b.x, acc[4]))));
    acc[5] = fmaf(w4.x, h0b.y, fmaf(w4.y, h1b.y, fmaf(w4.z, h2b.y, fmaf(w4.w, h3b.y, acc[5]))));
    acc[6] = fmaf(w4.x, h0b.z, fmaf(w4.y, h1b.z, fmaf(w4.z, h2b.z, fmaf(w4.w, h3b.z, acc[6]))));
    acc[7] = fmaf(w4.x, h0b.w, fmaf(w4.y, h1b.w, fmaf(w4.z, h2b.w, fmaf(w4.w, h3b.w, acc[7]))));
  }
  #pragma unroll
  for (int s=1; s<64; s<<=1){
    #pragma unroll
    for (int b=0;b<8;b++) acc[b] += __shfl_xor(acc[b], s, 64);
  }
  if (lane == 0){
    const float bm = db2[m];
    #pragma unroll
    for (int b=0;b<8;b++){
      const int t = b*1926 + m;
      out[t] = acc[b] + bm + oldv[t];
    }
  }
}

__launch_bounds__(256)
__global__ void transpose_x(const float* __restrict__ x, ushort* __restrict__ xt)
{
  const int idx = blockIdx.x*256 + threadIdx.x;
  const int b = idx >> 16, e = idx & 65535;
  const float* xb = x + (size_t)b*5*E_DIM + e;
  uint4 v;
  v.x = packbf(xb[0],               xb[(size_t)E_DIM]);
  v.y = packbf(xb[2*(size_t)E_DIM], xb[3*(size_t)E_DIM]);
  v.z = packbf(xb[4*(size_t)E_DIM], 0.f);
  v.w = 0u;
  *reinterpret_cast<uint4*>(xt + (size_t)idx*8) = v;
}

extern "C" void kernel_launch(void* const* d_in, const int* in_sizes, int n_in,
                              void* d_out, int out_size, void* d_ws, size_t ws_size,
                              hipStream_t stream)
{
  const float* x    = (const float*)d_in[0];
  const int*   gm   = (const int*)d_in[1];
  const float* oldv = (const float*)d_in[2];
  const float* w0 = (const float*)d_in[3],  *b0 = (const float*)d_in[4];
  const float* g0 = (const float*)d_in[5],  *be0= (const float*)d_in[6];
  const float* w1 = (const float*)d_in[7],  *b1 = (const float*)d_in[8];
  const float* g1 = (const float*)d_in[9],  *be1= (const float*)d_in[10];
  const float* w2 = (const float*)d_in[11], *b2 = (const float*)d_in[12];
  const float* g2 = (const float*)d_in[13], *be2= (const float*)d_in[14];
  const float* w3 = (const float*)d_in[15], *b3 = (const float*)d_in[16];
  const float* g3 = (const float*)d_in[17], *be3= (const float*)d_in[18];
  const float* dw1 = (const float*)d_in[19], *db1 = (const float*)d_in[20];
  const float* dw2 = (const float*)d_in[21], *db2 = (const float*)d_in[22];

  char* ws = (char*)d_ws;
  size_t off = 0;
  auto alloc = [&](size_t n){ size_t o = off; off += (n + 255) & ~(size_t)255; return o; };
  ushort* xt = (ushort*)(ws + alloc((size_t)BE_TOTAL*8*2));
  ushort* h0 = (ushort*)(ws + alloc((size_t)BE_TOTAL*16*2));
  char*   h1 = (char*)  (ws + alloc((size_t)BE_TOTAL*32));   // 2 fp8 planes
  char*   h2 = (char*)  (ws + alloc((size_t)BE_TOTAL*64));   // 4 fp8 planes
  char*   h3 = (char*)  (ws + alloc((size_t)BE_TOTAL*64));   // 4 fp8 planes
  float* part   = (float*)(ws + alloc((size_t)NB_STATS*128*4));
  float* spart  = (float*)(ws + alloc((size_t)4096*128*4));
  float* mpart  = (float*)(ws + alloc((size_t)128*128*4));
  float* ss0    = (float*)(ws + alloc(512));
  float* ss1    = (float*)(ws + alloc(512));
  float* ss2    = (float*)(ws + alloc(512));
  float* ss3    = (float*)(ws + alloc(512));
  float* ppart  = (float*)(ws + alloc((size_t)8*64*64*4));
  float* pooled = (float*)(ws + alloc(512*4));
  float* h1fc   = (float*)(ws + alloc(20000*4));
  ushort* w1i   = (ushort*)(ws + alloc((size_t)3*32*32*2));
  uchar*  w2i   = (uchar*) (ws + alloc((size_t)6*64*32));
  uchar*  w3i   = (uchar*) (ws + alloc((size_t)12*64*32));
  (void)ws_size; (void)in_sizes; (void)n_in; (void)out_size;

  const int CB = BE_TOTAL/256;   // 2048
  const int MB = BE_TOTAL/128;   // 4096

  transpose_x<<<CB,256,0,stream>>>(x, xt);
  wprep<16,32><<<2,256,0,stream>>>(w1, w1i);
  wprep8<32,64><<<6,256,0,stream>>>(w2, w2i);
  wprep8<64,64><<<12,256,0,stream>>>(w3, w3i);

  conv0_kernel<<<CB,256,0,stream>>>(xt, gm, w0, b0, h0);
  stats_kernel<16><<<NB_STATS,256,0,stream>>>(h0, part);
  finalize_stats<16><<<1,256,0,stream>>>(part, NB_STATS, g0, be0, 1.f, 1.f, ss0);

  // L1: bf16 in (h0), bf16 MFMA, fp8 out (stored = 16*true)
  mconv_mfma<16,32,false,false><<<MB,256,0,stream>>>(
      (const char*)h0, gm, (const char*)w1i, b1, 1.f, ss0, 16.f, h1, spart);
  merge_stats<32><<<128,256,0,stream>>>(spart, mpart);
  finalize_stats<32><<<1,256,0,stream>>>(mpart, 128, g1, be1, 1.f, 1.f/16.f, ss1);

  // L2: fp8 in (h1), fp8 MFMA (acc = 64*true), fp8 out (stored = 16*true)
  mconv_mfma<32,64,true,false><<<MB,256,0,stream>>>(
      h1, gm, (const char*)w2i, b2, 64.f, ss1, 0.25f, h2, spart);
  merge_stats<64><<<128,256,0,stream>>>(spart, mpart);
  finalize_stats<64><<<1,256,0,stream>>>(mpart, 128, g2, be2, 1.f/64.f, 1.f/16.f, ss2);

  // L3: fp8 in (h2), fp8 MFMA (acc = 64*true), fp8 planes out (stored = 16*true)
  mconv_mfma<64,64,true,false><<<MB,256,0,stream>>>(
      h2, gm, (const char*)w3i, b3, 64.f, ss2, 0.25f, h3, spart);
  merge_stats<64><<<128,256,0,stream>>>(spart, mpart);
  finalize_stats<64><<<1,256,0,stream>>>(mpart, 128, g3, be3, 1.f/64.f, 1.f/16.f, ss3);

  pool_kernel<<<512,256,0,stream>>>(h3, ss3, ppart);
  finalize_pool<<<1,512,0,stream>>>(ppart, pooled);
  fc1_kernel<<<10,256,0,stream>>>(pooled, dw1, db1, h1fc);
  fc2_kernel<<<482,256,0,stream>>>(h1fc, dw2, db2, oldv, (float*)d_out);
}

// Round 14
// 246.292 us; speedup vs baseline: 1.2643x; 1.0095x over previous
//
#include <hip/hip_runtime.h>

#define E_DIM 65536
#define BE_TOTAL 524288
#define EPS_BN 1e-5f
#define NB_STATS 256

typedef unsigned int uint;
typedef unsigned short ushort;
typedef unsigned char uchar;
typedef __attribute__((ext_vector_type(8))) short short8;   // 8 bf16 (4 VGPR)
typedef __attribute__((ext_vector_type(4))) float floatx4;

#define PB_FP8 ((size_t)BE_TOTAL*16)   // bytes per 16-ch fp8 plane

__device__ __forceinline__ float bflo(uint u){ return __uint_as_float(u << 16); }
__device__ __forceinline__ float bfhi(uint u){ return __uint_as_float(u & 0xffff0000u); }

__device__ __forceinline__ ushort pbf1(float a){
  uint ua = __float_as_uint(a);
  return (ushort)((ua + 0x7fffu + ((ua >> 16) & 1u)) >> 16);
}
__device__ __forceinline__ uint packbf(float a, float b){
  return (uint)pbf1(a) | ((uint)pbf1(b) << 16);
}
__device__ __forceinline__ void unpack8(uint4 v, float* x){
  x[0]=bflo(v.x); x[1]=bfhi(v.x); x[2]=bflo(v.y); x[3]=bfhi(v.y);
  x[4]=bflo(v.z); x[5]=bfhi(v.z); x[6]=bflo(v.w); x[7]=bfhi(v.w);
}
__device__ __forceinline__ uint4 pack8u(const float* z){
  uint4 v;
  v.x = packbf(z[0],z[1]); v.y = packbf(z[2],z[3]);
  v.z = packbf(z[4],z[5]); v.w = packbf(z[6],z[7]);
  return v;
}

// ---- fp8 e4m3 helpers ----
__device__ __forceinline__ uint2 pack8f8(const float* z){
  int lo = __builtin_amdgcn_cvt_pk_fp8_f32(z[0], z[1], 0,  false);
  lo     = __builtin_amdgcn_cvt_pk_fp8_f32(z[2], z[3], lo, true);
  int hi = __builtin_amdgcn_cvt_pk_fp8_f32(z[4], z[5], 0,  false);
  hi     = __builtin_amdgcn_cvt_pk_fp8_f32(z[6], z[7], hi, true);
  uint2 r; r.x = (uint)lo; r.y = (uint)hi; return r;
}
__device__ __forceinline__ void dec8f8(uint2 w, float* x){
  x[0]=__builtin_amdgcn_cvt_f32_fp8((int)w.x,0);
  x[1]=__builtin_amdgcn_cvt_f32_fp8((int)w.x,1);
  x[2]=__builtin_amdgcn_cvt_f32_fp8((int)w.x,2);
  x[3]=__builtin_amdgcn_cvt_f32_fp8((int)w.x,3);
  x[4]=__builtin_amdgcn_cvt_f32_fp8((int)w.y,0);
  x[5]=__builtin_amdgcn_cvt_f32_fp8((int)w.y,1);
  x[6]=__builtin_amdgcn_cvt_f32_fp8((int)w.y,2);
  x[7]=__builtin_amdgcn_cvt_f32_fp8((int)w.y,3);
}
__device__ __forceinline__ uchar f8byte(float v){
  return (uchar)(__builtin_amdgcn_cvt_pk_fp8_f32(v, 0.f, 0, false) & 0xff);
}

// ------------- weight relayout (fp8 image): rows 32B, groups 8B, ×64 ----
template<int CI, int CO>
__global__ void wprep8(const float* __restrict__ w, uchar* __restrict__ img)
{
  constexpr int CHUNKS = CI/16;
  const int t = blockIdx.x*256 + threadIdx.x;
  if (t >= CHUNKS*3*CO*4) return;
  const int g  = t & 3;
  const int o  = (t >> 2) % CO;
  const int ck = (t >> 2) / CO;
  const int chunk = ck / 3;
  const int ks    = ck % 3;
  float z[8];
  #pragma unroll
  for (int j8=0;j8<8;j8++){
    const int j = g*8 + j8;
    const int ft = ks*2 + (j>>4);
    const int ci = chunk*16 + (j & 15);
    z[j8] = (ft < 5) ? w[((size_t)o*CI + ci)*5 + ft] * 64.f : 0.f;   // SW=64
  }
  const int t4 = (o&3) ^ ((o>>2)&3);
  *reinterpret_cast<uint2*>(img + ((size_t)(ck*CO + o))*32 + ((g^t4)<<3)) = pack8f8(z);
}

// ---------------- MFMA mesh-conv (fused BN-stats epilogue) ----------------
// Input: CI/16 fp8 planes (16B rows). Output: fp8 planes or bf16 linear.
// F in LDS, double-buffered when CHUNKS>1.
template<int CI, int CO, bool IN_FP8, bool OUT_BF16LIN>
__launch_bounds__(256, 4)
__global__ void mconv_mfma(const char* __restrict__ hin,
                           const int* __restrict__ gemm,
                           const char* __restrict__ wimg,
                           const float* __restrict__ bias, float bscale,
                           const float* __restrict__ ss, float pkf,
                           char* __restrict__ hout,
                           float* __restrict__ spart)
{
  constexpr int CHUNKS = CI/16;
  constexpr int NT = CO/16;
  constexpr int AB  = IN_FP8 ? 32 : 64;               // FB row bytes
  constexpr int FBY = 3*128*AB;
  constexpr int NBUF = (CHUNKS > 1) ? 2 : 1;
  constexpr int OBB = 128*CO*(OUT_BF16LIN?2:1);
  constexpr int SBY = 4*2*CO*4;
  constexpr int SMEM = (NBUF*FBY > OBB+SBY) ? NBUF*FBY : (OBB+SBY);
  constexpr size_t PIN = IN_FP8 ? PB_FP8 : (size_t)BE_TOTAL*32;
  constexpr int RB = IN_FP8 ? 16 : 32;                // input row bytes
  __shared__ char smem[SMEM];
  char* FB = smem;

  const int tid = threadIdx.x;
  const int bid = blockIdx.x;            // 4096 = 8 (batch=XCD) * 512
  const int b   = bid & 7;
  const int e0  = (bid >> 3) * 128;
  const size_t bbase = (size_t)b << 16;

  const int lane = tid & 63;
  const int wv   = tid >> 6;
  const int col  = lane & 15;
  const int kg   = lane >> 4;
  const int t4c  = (col & 3) ^ ((col >> 2) & 3);

  floatx4 acc[2][NT];
  #pragma unroll
  for (int n=0;n<NT;n++){
    const float bv = bias[n*16 + col] * bscale;
    #pragma unroll
    for (int mt=0;mt<2;mt++) acc[mt][n] = (floatx4){bv,bv,bv,bv};
  }

  // gather byte-offsets within a plane: 2 threads/element, hh = 8-ch half
  const int el = tid >> 1;
  const int hh = tid & 1;
  const int t4e = (el&3) ^ ((el>>2)&3);
  uint off[5];
  {
    const size_t idx = bbase + (size_t)(e0 + el);
    const int4 g4 = *reinterpret_cast<const int4*>(gemm + idx*4);
    off[0] = (uint)(idx*RB + hh*(RB/2));
    off[1] = (uint)((bbase + (size_t)(uint)g4.x)*RB + hh*(RB/2));
    off[2] = (uint)((bbase + (size_t)(uint)g4.y)*RB + hh*(RB/2));
    off[3] = (uint)((bbase + (size_t)(uint)g4.z)*RB + hh*(RB/2));
    off[4] = (uint)((bbase + (size_t)(uint)g4.w)*RB + hh*(RB/2));
  }

  // BN + features + pack into FB buffer (v[5][8] already decoded)
  auto BUILD = [&](float (&v)[5][8], int chunk, char* FBb){
    const int cb = chunk*16 + hh*8;
    #pragma unroll
    for (int c=0;c<8;c++){
      const float sc = ss[cb+c], sh = ss[CI+cb+c];
      #pragma unroll
      for (int r=0;r<5;r++) v[r][c] = fmaxf(fmaf(v[r][c], sc, sh), 0.f);
    }
    float y[5][8];
    #pragma unroll
    for (int c=0;c<8;c++){
      y[0][c] = v[0][c];
      y[1][c] = v[1][c] + v[3][c];
      y[2][c] = v[2][c] + v[4][c];
      y[3][c] = fabsf(v[1][c] - v[3][c]);
      y[4][c] = fabsf(v[2][c] - v[4][c]);
    }
    if constexpr (IN_FP8){
      #pragma unroll
      for (int ks=0; ks<3; ks++){
        char* base = FBb + ks*(128*32) + el*32;
        *reinterpret_cast<uint2*>(base + (((0+hh)^t4e)<<3)) = pack8f8(y[2*ks]);
        if (ks < 2){
          *reinterpret_cast<uint2*>(base + (((2+hh)^t4e)<<3)) = pack8f8(y[2*ks+1]);
        } else {
          uint2 zz; zz.x=0u; zz.y=0u;
          *reinterpret_cast<uint2*>(base + (((2+hh)^t4e)<<3)) = zz;
        }
      }
    } else {
      #pragma unroll
      for (int ks=0; ks<3; ks++){
        char* base = FBb + ks*8192 + el*64;
        *reinterpret_cast<uint4*>(base + (((0+hh)^t4e)<<4)) = pack8u(y[2*ks]);
        if (ks < 2){
          *reinterpret_cast<uint4*>(base + (((2+hh)^t4e)<<4)) = pack8u(y[2*ks+1]);
        } else {
          const uint4 zz = {0,0,0,0};
          *reinterpret_cast<uint4*>(base + (((2+hh)^t4e)<<4)) = zz;
        }
      }
    }
  };

  auto MMA = [&](int chunk, const char* FBb){
    const char* WG = wimg + (size_t)chunk*(3*CO*AB);
    #pragma unroll
    for (int ks=0; ks<3; ks++){
      if constexpr (IN_FP8){
        long long bf[NT];
        #pragma unroll
        for (int n=0;n<NT;n++)
          bf[n] = *reinterpret_cast<const long long*>(WG + ks*(CO*32) + n*512 + col*32 + ((kg^t4c)<<3));
        #pragma unroll
        for (int mt=0;mt<2;mt++){
          const long long af = *reinterpret_cast<const long long*>(
              FBb + ks*(128*32) + (wv*32+mt*16+col)*32 + ((kg^t4c)<<3));
          #pragma unroll
          for (int n=0;n<NT;n++)
            acc[mt][n] = __builtin_amdgcn_mfma_f32_16x16x32_fp8_fp8(af, bf[n], acc[mt][n], 0, 0, 0);
        }
      } else {
        short8 bf[NT];
        #pragma unroll
        for (int n=0;n<NT;n++)
          bf[n] = *reinterpret_cast<const short8*>(WG + ks*(CO*64) + n*1024 + col*64 + ((kg^t4c)<<4));
        #pragma unroll
        for (int mt=0;mt<2;mt++){
          const short8 af = *reinterpret_cast<const short8*>(
              FBb + ks*8192 + (wv*32+mt*16+col)*64 + ((kg^t4c)<<4));
          #pragma unroll
          for (int n=0;n<NT;n++)
            acc[mt][n] = __builtin_amdgcn_mfma_f32_16x16x32_bf16(af, bf[n], acc[mt][n], 0, 0, 0);
        }
      }
    }
  };

  if constexpr (CHUNKS == 1){
    float v[5][8];
    uint2 q[5];
    #pragma unroll
    for (int r=0;r<5;r++) q[r] = *reinterpret_cast<const uint2*>(hin + off[r]);
    #pragma unroll
    for (int r=0;r<5;r++) dec8f8(q[r], v[r]);
    BUILD(v, 0, FB);
    __syncthreads();
    MMA(0, FB);
  } else {
    {
      uint2 q[5];
      #pragma unroll
      for (int r=0;r<5;r++) q[r] = *reinterpret_cast<const uint2*>(hin + off[r]);
      float v[5][8];
      #pragma unroll
      for (int r=0;r<5;r++) dec8f8(q[r], v[r]);
      BUILD(v, 0, FB);
    }
    __syncthreads();
    #pragma unroll
    for (int c=0; c<CHUNKS; ++c){
      uint2 qn[5];
      if (c+1 < CHUNKS){
        const char* hp = hin + (size_t)(c+1)*PIN;
        #pragma unroll
        for (int r=0;r<5;r++) qn[r] = *reinterpret_cast<const uint2*>(hp + off[r]);
      }
      MMA(c, FB + (c&1)*FBY);
      if (c+1 < CHUNKS){
        float v[5][8];
        #pragma unroll
        for (int r=0;r<5;r++) dec8f8(qn[r], v[r]);
        BUILD(v, c+1, FB + ((c+1)&1)*FBY);
        __syncthreads();
      }
    }
  }

  // ---- per-lane BN-stats partials (registers only) ----
  float sred[2*NT];
  #pragma unroll
  for (int n=0;n<NT;n++){
    float s = 0.f, q2 = 0.f;
    #pragma unroll
    for (int mt=0;mt<2;mt++){
      #pragma unroll
      for (int r=0;r<4;r++){ const float vv = acc[mt][n][r]; s += vv; q2 = fmaf(vv,vv,q2); }
    }
    s  += __shfl_xor(s,16,64);  s  += __shfl_xor(s,32,64);
    q2 += __shfl_xor(q2,16,64); q2 += __shfl_xor(q2,32,64);
    sred[n] = s; sred[NT+n] = q2;
  }

  __syncthreads();
  float* SB = reinterpret_cast<float*>(smem + OBB);   // [4][2*CO]
  if constexpr (OUT_BF16LIN){
    ushort* OB = reinterpret_cast<ushort*>(smem);
    #pragma unroll
    for (int mt=0; mt<2; mt++){
      const int er = wv*32 + mt*16 + 4*kg;
      #pragma unroll
      for (int n=0;n<NT;n++){
        #pragma unroll
        for (int r=0;r<4;r++)
          OB[(er+r)*CO + n*16 + col] = pbf1(acc[mt][n][r]);
      }
    }
  } else {
    uchar* OB = reinterpret_cast<uchar*>(smem);
    #pragma unroll
    for (int mt=0; mt<2; mt++){
      const int er = wv*32 + mt*16 + 4*kg;
      #pragma unroll
      for (int n=0;n<NT;n++){
        #pragma unroll
        for (int r=0;r<4;r++)
          OB[(er+r)*CO + n*16 + col] = f8byte(acc[mt][n][r] * pkf);
      }
    }
  }
  if (kg == 0){
    #pragma unroll
    for (int n=0;n<NT;n++){
      SB[wv*2*CO + n*16 + col]      = sred[n];
      SB[wv*2*CO + CO + n*16 + col] = sred[NT+n];
    }
  }
  __syncthreads();
  if constexpr (OUT_BF16LIN){
    const uint4* src = reinterpret_cast<const uint4*>(smem);
    uint4* dst = reinterpret_cast<uint4*>(hout + (bbase + (size_t)e0)*CO*2);
    constexpr int NV = 128*CO/8;
    for (int i=tid; i<NV; i+=256) dst[i] = src[i];
  } else {
    constexpr int NV = 128*CO/16;     // one uint4 = one 16-ch fp8 plane row
    for (int i=tid; i<NV; i+=256){
      const int pl  = i >> 7;
      const int elx = i & 127;
      const uint4 vv = *reinterpret_cast<const uint4*>(smem + elx*CO + pl*16);
      *reinterpret_cast<uint4*>(hout + (size_t)pl*PB_FP8 + (bbase + (size_t)(e0+elx))*16) = vv;
    }
  }
  if (tid < 2*CO){
    spart[(size_t)bid*2*CO + tid] =
      SB[tid] + SB[2*CO + tid] + SB[4*CO + tid] + SB[6*CO + tid];
  }
}

// ---------------- conv0: CI=5 (padded-8 rows) -> CO=16, VALU, fp8 out ------
__launch_bounds__(256)
__global__ void conv0_kernel(const ushort* __restrict__ hin,
                             const int* __restrict__ gemm,
                             const float* __restrict__ w,
                             const float* __restrict__ bias,
                             char* __restrict__ hout)
{
  const int bid = blockIdx.x;                     // 2048 = 8 XCD * 256
  const int swz = (bid & 7) * 256 + (bid >> 3);
  const int idx = swz * 256 + threadIdx.x;
  const int b = idx >> 16;
  const int4 g4 = *reinterpret_cast<const int4*>(gemm + (size_t)idx * 4);
  const size_t bbase = (size_t)b << 16;
  float xc[8], n0[8], n1[8], n2[8], n3[8];
  unpack8(*reinterpret_cast<const uint4*>(hin + (size_t)idx*8), xc);
  unpack8(*reinterpret_cast<const uint4*>(hin + (bbase + (size_t)(uint)g4.x)*8), n0);
  unpack8(*reinterpret_cast<const uint4*>(hin + (bbase + (size_t)(uint)g4.y)*8), n1);
  unpack8(*reinterpret_cast<const uint4*>(hin + (bbase + (size_t)(uint)g4.z)*8), n2);
  unpack8(*reinterpret_cast<const uint4*>(hin + (bbase + (size_t)(uint)g4.w)*8), n3);
  float f1[5], f2[5], f3[5], f4[5];
  #pragma unroll
  for (int c=0;c<5;c++){
    f1[c] = n0[c] + n2[c];
    f2[c] = n1[c] + n3[c];
    f3[c] = fabsf(n0[c] - n2[c]);
    f4[c] = fabsf(n1[c] - n3[c]);
  }
  float acc[16];
  #pragma unroll
  for (int o=0;o<16;o++){
    const float* wp = w + (size_t)o*25;
    float a = bias[o];
    #pragma unroll
    for (int c=0;c<5;c++){
      a = fmaf(xc[c], wp[c*5+0], a);
      a = fmaf(f1[c], wp[c*5+1], a);
      a = fmaf(f2[c], wp[c*5+2], a);
      a = fmaf(f3[c], wp[c*5+3], a);
      a = fmaf(f4[c], wp[c*5+4], a);
    }
    acc[o] = a * 16.f;    // stored = 16*true
  }
  const uint2 lo = pack8f8(acc);
  const uint2 hi = pack8f8(acc + 8);
  uint4 v; v.x = lo.x; v.y = lo.y; v.z = hi.x; v.w = hi.y;
  *reinterpret_cast<uint4*>(hout + (size_t)idx * 16) = v;
}

// ---------------- BN stats over fp8 plane (h0, 16 ch) --------------
__launch_bounds__(256)
__global__ void stats8_16(const char* __restrict__ h, float* __restrict__ part)
{
  const int tid = threadIdx.x;
  const int cg  = tid & 1;           // 8-ch half
  const int row = tid >> 1;          // 0..127
  float s[8], q[8];
  #pragma unroll
  for (int i=0;i<8;i++){ s[i]=0.f; q[i]=0.f; }
  for (long idx = (long)blockIdx.x*128 + row; idx < BE_TOTAL; idx += (long)gridDim.x*128){
    uint2 v = *reinterpret_cast<const uint2*>(h + idx*16 + cg*8);
    float x[8]; dec8f8(v, x);
    #pragma unroll
    for (int i=0;i<8;i++){ s[i]+=x[i]; q[i]+=x[i]*x[i]; }
  }
  __shared__ float lds[256*16];
  #pragma unroll
  for (int i=0;i<8;i++){ lds[tid*16+i]=s[i]; lds[tid*16+8+i]=q[i]; }
  __syncthreads();
  if (tid < 32){
    const int st = tid / 16;         // 0=sum, 1=sumsq
    const int c  = tid % 16;
    const int cgg = c >> 3, ci = c & 7;
    float t = 0.f;
    for (int r=0;r<128;r++) t += lds[(r*2+cgg)*16 + st*8 + ci];
    part[(size_t)blockIdx.x*32 + tid] = t;
  }
}

template<int CO>
__launch_bounds__(256)
__global__ void merge_stats(const float* __restrict__ in, float* __restrict__ out)
{
  const int t = threadIdx.x;
  if (t >= 2*CO) return;
  const int j = blockIdx.x;            // 128
  float s = 0.f;
  #pragma unroll 4
  for (int r = 0; r < 32; r++) s += in[((size_t)(j*32 + r))*(2*CO) + t];
  out[(size_t)j*(2*CO) + t] = s;
}

// Parallel finalize with accumulator/storage scale folding.
template<int CO>
__launch_bounds__(256)
__global__ void finalize_stats(const float* __restrict__ part, int nblk,
                               const float* __restrict__ g, const float* __restrict__ beta,
                               float invSa, float invSt, float* __restrict__ ss)
{
  constexpr int Q = 256 / CO;
  const int t = threadIdx.x;
  const int c = t % CO;
  const int qq = t / CO;
  float s = 0.f, sq = 0.f;
  for (int b = qq; b < nblk; b += Q){
    s  += part[(size_t)b*2*CO + c];
    sq += part[(size_t)b*2*CO + CO + c];
  }
  __shared__ float lsum[256], lsq[256];
  lsum[t] = s; lsq[t] = sq;
  __syncthreads();
  if (t < CO){
    float ts = 0.f, tq = 0.f;
    #pragma unroll
    for (int r = 0; r < Q; r++){ ts += lsum[r*CO + t]; tq += lsq[r*CO + t]; }
    const float inv = 1.f / (float)BE_TOTAL;
    const float mean = ts * inv * invSa;
    const float var  = tq * inv * invSa * invSa - mean*mean;
    const float scale = g[t] * rsqrtf(var + EPS_BN);
    ss[t]      = scale * invSt;
    ss[CO + t] = beta[t] - mean * scale;
  }
}

// pool over fp8 planes: h3 = 4 planes of [b][e][16] fp8
__launch_bounds__(256)
__global__ void pool_kernel(const char* __restrict__ h3, const float* __restrict__ ss,
                            float* __restrict__ part)
{
  const int tid = threadIdx.x;
  const int cg  = tid % 8;          // 8-ch group: plane cg>>1, half cg&1
  const int row = tid / 8;
  const int b   = blockIdx.x >> 6;
  const int blk = blockIdx.x & 63;
  float sc[8], sh[8];
  #pragma unroll
  for (int i=0;i<8;i++){ sc[i]=ss[cg*8+i]; sh[i]=ss[64+cg*8+i]; }
  float s[8];
  #pragma unroll
  for (int i=0;i<8;i++) s[i]=0.f;
  const char* hp = h3 + (size_t)(cg>>1)*PB_FP8 + (cg&1)*8;
  for (int e = blk*32 + row; e < E_DIM; e += 64*32){
    size_t idx = ((size_t)b << 16) + e;
    uint2 v = *reinterpret_cast<const uint2*>(hp + idx*16);
    float x[8]; dec8f8(v, x);
    #pragma unroll
    for (int i=0;i<8;i++) s[i] += fmaxf(fmaf(x[i], sc[i], sh[i]), 0.f);
  }
  __shared__ float lds[256*8];
  #pragma unroll
  for (int i=0;i<8;i++) lds[tid*8+i]=s[i];
  __syncthreads();
  if (tid < 64){
    const int c = tid, cgg = c >> 3, ci = c & 7;
    float t = 0.f;
    for (int r=0;r<32;r++) t += lds[(r*8+cgg)*8 + ci];
    part[((size_t)b*64 + blk)*64 + c] = t;
  }
}

__global__ void finalize_pool(const float* __restrict__ part, float* __restrict__ pooled)
{
  const int t = threadIdx.x;
  const int b = t >> 6, c = t & 63;
  float s = 0.f;
  for (int blk=0;blk<64;blk++) s += part[((size_t)b*64 + blk)*64 + c];
  pooled[t] = s * (1.f / (float)E_DIM);
}

__global__ void fc1_kernel(const float* __restrict__ pooled, const float* __restrict__ dw1,
                           const float* __restrict__ db1, float* __restrict__ h1t)
{
  const int n = blockIdx.x*blockDim.x + threadIdx.x;
  if (n >= 2500) return;
  float acc[8];
  const float bias = db1[n];
  #pragma unroll
  for (int b=0;b<8;b++) acc[b]=bias;
  const float* wr = dw1 + (size_t)n*64;
  #pragma unroll
  for (int c=0;c<64;c++){
    float wv = wr[c];
    #pragma unroll
    for (int b=0;b<8;b++) acc[b] = fmaf(wv, pooled[b*64+c], acc[b]);
  }
  #pragma unroll
  for (int b=0;b<8;b++) h1t[(size_t)n*8 + b] = fmaxf(acc[b], 0.f);
}

__launch_bounds__(256)
__global__ void fc2_kernel(const float* __restrict__ h1t, const float* __restrict__ dw2,
                           const float* __restrict__ db2, const float* __restrict__ oldv,
                           float* __restrict__ out)
{
  const int wv   = threadIdx.x >> 6;
  const int lane = threadIdx.x & 63;
  const int m = blockIdx.x*4 + wv;
  if (m >= 1926) return;
  const float4* wr = reinterpret_cast<const float4*>(dw2 + (size_t)m*2500);
  float acc[8];
  #pragma unroll
  for (int b=0;b<8;b++) acc[b]=0.f;
  for (int j = lane; j < 625; j += 64){
    const float4 w4 = wr[j];
    const float4* hp = reinterpret_cast<const float4*>(h1t + (size_t)j*32);
    const float4 h0a = hp[0], h0b = hp[1];
    const float4 h1a = hp[2], h1b = hp[3];
    const float4 h2a = hp[4], h2b = hp[5];
    const float4 h3a = hp[6], h3b = hp[7];
    acc[0] = fmaf(w4.x, h0a.x, fmaf(w4.y, h1a.x, fmaf(w4.z, h2a.x, fmaf(w4.w, h3a.x, acc[0]))));
    acc[1] = fmaf(w4.x, h0a.y, fmaf(w4.y, h1a.y, fmaf(w4.z, h2a.y, fmaf(w4.w, h3a.y, acc[1]))));
    acc[2] = fmaf(w4.x, h0a.z, fmaf(w4.y, h1a.z, fmaf(w4.z, h2a.z, fmaf(w4.w, h3a.z, acc[2]))));
    acc[3] = fmaf(w4.x, h0a.w, fmaf(w4.y, h1a.w, fmaf(w4.z, h2a.w, fmaf(w4.w, h3a.w, acc[3]))));
    acc[4] = fmaf(w4.x, h0b.x, fmaf(w4.y, h1b.x, fmaf(w4.z, h2b.x, fmaf(w4.w, h3b.x, acc[4]))));
    acc[5] = fmaf(w4.x, h0b.y, fmaf(w4.y, h1b.y, fmaf(w4.z, h2b.y, fmaf(w4.w, h3b.y, acc[5]))));
    acc[6] = fmaf(w4.x, h0b.z, fmaf(w4.y, h1b.z, fmaf(w4.z, h2b.z, fmaf(w4.w, h3b.z, acc[6]))));
    acc[7] = fmaf(w4.x, h0b.w, fmaf(w4.y, h1b.w, fmaf(w4.z, h2b.w, fmaf(w4.w, h3b.w, acc[7]))));
  }
  #pragma unroll
  for (int s=1; s<64; s<<=1){
    #pragma unroll
    for (int b=0;b<8;b++) acc[b] += __shfl_xor(acc[b], s, 64);
  }
  if (lane == 0){
    const float bm = db2[m];
    #pragma unroll
    for (int b=0;b<8;b++){
      const int t = b*1926 + m;
      out[t] = acc[b] + bm + oldv[t];
    }
  }
}

__launch_bounds__(256)
__global__ void transpose_x(const float* __restrict__ x, ushort* __restrict__ xt)
{
  const int idx = blockIdx.x*256 + threadIdx.x;
  const int b = idx >> 16, e = idx & 65535;
  const float* xb = x + (size_t)b*5*E_DIM + e;
  uint4 v;
  v.x = packbf(xb[0],               xb[(size_t)E_DIM]);
  v.y = packbf(xb[2*(size_t)E_DIM], xb[3*(size_t)E_DIM]);
  v.z = packbf(xb[4*(size_t)E_DIM], 0.f);
  v.w = 0u;
  *reinterpret_cast<uint4*>(xt + (size_t)idx*8) = v;
}

extern "C" void kernel_launch(void* const* d_in, const int* in_sizes, int n_in,
                              void* d_out, int out_size, void* d_ws, size_t ws_size,
                              hipStream_t stream)
{
  const float* x    = (const float*)d_in[0];
  const int*   gm   = (const int*)d_in[1];
  const float* oldv = (const float*)d_in[2];
  const float* w0 = (const float*)d_in[3],  *b0 = (const float*)d_in[4];
  const float* g0 = (const float*)d_in[5],  *be0= (const float*)d_in[6];
  const float* w1 = (const float*)d_in[7],  *b1 = (const float*)d_in[8];
  const float* g1 = (const float*)d_in[9],  *be1= (const float*)d_in[10];
  const float* w2 = (const float*)d_in[11], *b2 = (const float*)d_in[12];
  const float* g2 = (const float*)d_in[13], *be2= (const float*)d_in[14];
  const float* w3 = (const float*)d_in[15], *b3 = (const float*)d_in[16];
  const float* g3 = (const float*)d_in[17], *be3= (const float*)d_in[18];
  const float* dw1 = (const float*)d_in[19], *db1 = (const float*)d_in[20];
  const float* dw2 = (const float*)d_in[21], *db2 = (const float*)d_in[22];

  char* ws = (char*)d_ws;
  size_t off = 0;
  auto alloc = [&](size_t n){ size_t o = off; off += (n + 255) & ~(size_t)255; return o; };
  ushort* xt = (ushort*)(ws + alloc((size_t)BE_TOTAL*8*2));
  char*   h0 = (char*)  (ws + alloc((size_t)BE_TOTAL*16));   // 1 fp8 plane
  char*   h1 = (char*)  (ws + alloc((size_t)BE_TOTAL*32));   // 2 fp8 planes
  char*   h2 = (char*)  (ws + alloc((size_t)BE_TOTAL*64));   // 4 fp8 planes
  char*   h3 = (char*)  (ws + alloc((size_t)BE_TOTAL*64));   // 4 fp8 planes
  float* part   = (float*)(ws + alloc((size_t)NB_STATS*128*4));
  float* spart  = (float*)(ws + alloc((size_t)4096*128*4));
  float* mpart  = (float*)(ws + alloc((size_t)128*128*4));
  float* ss0    = (float*)(ws + alloc(512));
  float* ss1    = (float*)(ws + alloc(512));
  float* ss2    = (float*)(ws + alloc(512));
  float* ss3    = (float*)(ws + alloc(512));
  float* ppart  = (float*)(ws + alloc((size_t)8*64*64*4));
  float* pooled = (float*)(ws + alloc(512*4));
  float* h1fc   = (float*)(ws + alloc(20000*4));
  uchar*  w1i   = (uchar*) (ws + alloc((size_t)3*32*32));
  uchar*  w2i   = (uchar*) (ws + alloc((size_t)6*64*32));
  uchar*  w3i   = (uchar*) (ws + alloc((size_t)12*64*32));
  (void)ws_size; (void)in_sizes; (void)n_in; (void)out_size;

  const int CB = BE_TOTAL/256;   // 2048
  const int MB = BE_TOTAL/128;   // 4096

  transpose_x<<<CB,256,0,stream>>>(x, xt);
  wprep8<16,32><<<2,256,0,stream>>>(w1, w1i);
  wprep8<32,64><<<6,256,0,stream>>>(w2, w2i);
  wprep8<64,64><<<12,256,0,stream>>>(w3, w3i);

  conv0_kernel<<<CB,256,0,stream>>>(xt, gm, w0, b0, h0);
  stats8_16<<<NB_STATS,256,0,stream>>>(h0, part);
  finalize_stats<16><<<1,256,0,stream>>>(part, NB_STATS, g0, be0, 1.f/16.f, 1.f/16.f, ss0);

  // L1: fp8 in (h0 = 16*true), fp8 MFMA (acc = 64*true), fp8 out (stored = 16*true)
  mconv_mfma<16,32,true,false><<<MB,256,0,stream>>>(
      h0, gm, (const char*)w1i, b1, 64.f, ss0, 0.25f, h1, spart);
  merge_stats<32><<<128,256,0,stream>>>(spart, mpart);
  finalize_stats<32><<<1,256,0,stream>>>(mpart, 128, g1, be1, 1.f/64.f, 1.f/16.f, ss1);

  // L2: fp8 in (h1), fp8 MFMA (acc = 64*true), fp8 out (stored = 16*true)
  mconv_mfma<32,64,true,false><<<MB,256,0,stream>>>(
      h1, gm, (const char*)w2i, b2, 64.f, ss1, 0.25f, h2, spart);
  merge_stats<64><<<128,256,0,stream>>>(spart, mpart);
  finalize_stats<64><<<1,256,0,stream>>>(mpart, 128, g2, be2, 1.f/64.f, 1.f/16.f, ss2);

  // L3: fp8 in (h2), fp8 MFMA (acc = 64*true), fp8 planes out (stored = 16*true)
  mconv_mfma<64,64,true,false><<<MB,256,0,stream>>>(
      h2, gm, (const char*)w3i, b3, 64.f, ss2, 0.25f, h3, spart);
  merge_stats<64><<<128,256,0,stream>>>(spart, mpart);
  finalize_stats<64><<<1,256,0,stream>>>(mpart, 128, g3, be3, 1.f/64.f, 1.f/16.f, ss3);

  pool_kernel<<<512,256,0,stream>>>(h3, ss3, ppart);
  finalize_pool<<<1,512,0,stream>>>(ppart, pooled);
  fc1_kernel<<<10,256,0,stream>>>(pooled, dw1, db1, h1fc);
  fc2_kernel<<<482,256,0,stream>>>(h1fc, dw2, db2, oldv, (float*)d_out);
}